// Round 17
// baseline (137.204 us; speedup 1.0000x reference)
//
#include <hip/hip_runtime.h>
#include <hip/hip_bf16.h>
#include <stdint.h>

typedef unsigned short u16;
typedef unsigned int u32;
typedef __attribute__((ext_vector_type(8))) short short8;
typedef __attribute__((ext_vector_type(4))) float f32x4;
typedef __attribute__((ext_vector_type(4))) unsigned int u32x4;
typedef __attribute__((ext_vector_type(4))) unsigned short u16x4;

#define MFMA16(a, b, c) __builtin_amdgcn_mfma_f32_16x16x32_bf16((a), (b), (c), 0, 0, 0)

__device__ __forceinline__ u16 f2bf(float f) {
    union { float f; uint32_t u; } v; v.f = f;
    return (u16)((v.u + 0x7FFFu + ((v.u >> 16) & 1u)) >> 16);
}
__device__ __forceinline__ u16 f2bf_up(float f) {  // round-half-up, f >= 0
    union { float f; uint32_t u; } v; v.f = f;
    return (u16)((v.u + 0x8000u) >> 16);
}

// async global -> LDS, 16 bytes per lane (dest must be linear: base + lane*16)
__device__ __forceinline__ void gl_lds16(const u16* g, u16* l) {
    __builtin_amdgcn_global_load_lds(
        (const __attribute__((address_space(1))) u32*)g,
        (__attribute__((address_space(3))) u32*)l,
        16, 0, 0);
}

// ---------------- merged convert kernel (one launch) ----------------

__global__ __launch_bounds__(256) void k_cvt(const float* __restrict__ x,
                                             const float* __restrict__ wq,
                                             const float* __restrict__ wp,
                                             u16* __restrict__ xb,
                                             u16* __restrict__ outq,
                                             u16* __restrict__ outp) {
    __shared__ u16 t[64][72];
    if (blockIdx.x < 6144) {
        int i = (blockIdx.x * 256 + threadIdx.x) * 4;
        f32x4 v = *(const f32x4*)(x + i);
        u16x4 o;
        o[0] = f2bf(v[0]); o[1] = f2bf(v[1]); o[2] = f2bf(v[2]); o[3] = f2bf(v[3]);
        *(u16x4*)(xb + i) = o;
        return;
    }
    int bid = blockIdx.x - 6144;          // 0..575
    int bx = bid % 48, kb = (bid / 48) * 64;
    const float* in; u16* out; int N, nb;
    if (bx < 36) { in = wq; out = outq; N = 2304; nb = bx * 64; }
    else         { in = wp; out = outp; N = 768;  nb = (bx - 36) * 64; }
    const int tid = threadIdx.x;
    const int r = tid >> 4, c4 = (tid & 15) << 2;
#pragma unroll
    for (int p = 0; p < 4; ++p) {
        int k = r + p * 16;
        f32x4 v = *(const f32x4*)&in[(size_t)(kb + k) * N + nb + c4];
#pragma unroll
        for (int q = 0; q < 4; ++q) t[c4 + q][k] = f2bf(v[q]);
    }
    __syncthreads();
#pragma unroll
    for (int p = 0; p < 4; ++p) {
        int nn = r + p * 16;
        u16x4 o;
#pragma unroll
        for (int q = 0; q < 4; ++q) o[q] = t[nn][c4 + q];
        *(u16x4*)&out[(size_t)(nb + nn) * 768 + kb + c4] = o;
    }
}

// ---------------- GEMM1: 128x144 tile, BK=64, dbuf 2-phase; grid 1024 = exactly 2 rounds ----------------

__global__ __launch_bounds__(256) void k_gemm_qkv(const u16* __restrict__ A,
                                                  const u16* __restrict__ BT,
                                                  const float* __restrict__ bias,
                                                  u16* __restrict__ qkv,
                                                  u16* __restrict__ Vtg) {
    extern __shared__ __align__(16) u16 lds[];   // 2 * 17408 u16
    const int tid = threadIdx.x;
    int id = blockIdx.x;                        // 1024 blocks
    int nid = (id & 7) * 128 + (id >> 3);       // XCD-chunked remap (1024 % 8 == 0)
    int by = nid >> 4, bx = nid & 15;
    const int m0 = by * 128, n0 = bx * 144;

    const u16* Asrc = A + (size_t)m0 * 768;
    const u16* Bsrc = BT + (size_t)n0 * 768;

    const int lane = tid & 63, wave = tid >> 6;
    const int g = lane >> 4, lr = lane & 15;

#define STAGE_QKV(K0, DST) do {                                                   \
    u16* dA_ = (DST);                                                             \
    u16* dB_ = (DST) + 8192;                                                      \
    _Pragma("unroll") for (int it = 0; it < 4; ++it) {                            \
        int c_ = tid + it * 256;                                                  \
        int r_ = c_ >> 3, s_ = c_ & 7, u_ = s_ ^ (r_ & 7);                        \
        gl_lds16(&Asrc[(size_t)r_ * 768 + (K0) + u_ * 8], &dA_[c_ * 8]);          \
        gl_lds16(&Bsrc[(size_t)r_ * 768 + (K0) + u_ * 8], &dB_[c_ * 8]);          \
    }                                                                             \
    if (tid < 128) {                                                              \
        int c_ = 1024 + tid;                                                      \
        int r_ = c_ >> 3, s_ = c_ & 7, u_ = s_ ^ (r_ & 7);                        \
        gl_lds16(&Bsrc[(size_t)r_ * 768 + (K0) + u_ * 8], &dB_[c_ * 8]);          \
    }                                                                             \
} while (0)

    f32x4 acc[2][9];
#pragma unroll
    for (int i = 0; i < 2; ++i)
#pragma unroll
        for (int j = 0; j < 9; ++j) acc[i][j] = (f32x4){0.f, 0.f, 0.f, 0.f};

    STAGE_QKV(0, lds);
    __syncthreads();

    for (int t = 0; t < 12; ++t) {
        const int cur = t & 1;
        if (t < 11) STAGE_QKV((t + 1) * 64, &lds[(cur ^ 1) * 17408]);
        const u16* As = &lds[cur * 17408];
        const u16* Bs = As + 8192;
#pragma unroll
        for (int kk = 0; kk < 2; ++kk) {
            const int slot = ((4 * kk + g) ^ (lr & 7)) << 3;
            short8 af[2], bfv[9];
#pragma unroll
            for (int i = 0; i < 2; ++i)
                af[i] = *(const short8*)&As[(32 * wave + 16 * i + lr) * 64 + slot];
#pragma unroll
            for (int j = 0; j < 9; ++j)
                bfv[j] = *(const short8*)&Bs[(16 * j + lr) * 64 + slot];
#pragma unroll
            for (int i = 0; i < 2; ++i)
#pragma unroll
                for (int j = 0; j < 9; ++j)
                    acc[i][j] = MFMA16(af[i], bfv[j], acc[i][j]);
        }
        if (t < 11) __syncthreads();
    }
#undef STAGE_QKV

    const float CS = 0.14724449f; // 1/sqrt(96) * log2(e)
#pragma unroll
    for (int i = 0; i < 2; ++i) {
        int row = m0 + 32 * wave + 16 * i + 4 * g;
#pragma unroll
        for (int j = 0; j < 9; ++j) {
            int col = n0 + 16 * j + lr;
            float bsv = bias[col];
            if (col < 1536) {
                float sc = (col < 768) ? CS : 1.0f;
#pragma unroll
                for (int r = 0; r < 4; ++r)
                    qkv[(size_t)(row + r) * 2304 + col] = f2bf((acc[i][j][r] + bsv) * sc);
            } else {
                int jj = col - 1536;
                int h = jj / 96, d = jj - h * 96;
                int t2 = row & 1023, bb = row >> 10;
                int bh = bb * 8 + h;
                u16x4 vv;
#pragma unroll
                for (int r = 0; r < 4; ++r) vv[r] = f2bf(acc[i][j][r] + bsv);
                *(u16x4*)&Vtg[((size_t)bh * 96 + d) * 1024 + t2] = vv;
            }
        }
    }
}

// ---------------- flash attention: pipelined QK + V-in-registers + swapped PV (O^T) ----------------
// Base = r15 proven structure (pipelined QK s4a/s4b, K dbuf staged 2-ahead, 1 barrier/kt).
// V is NOT staged in LDS: vf[6][2] fragments loaded directly from Vtg (A-operand layout),
// reloaded right AFTER PV consumes them -> a full phase (~barrier+QK+softmax) covers L2 latency.
// PV computes O^T = mfma(A=V^T, B=P^T): per-lane fragment data identical to the unswapped form;
// output lane layout O[q=lr][d=16c+4g+r] -> vectorized u16x4 epilogue + single reciprocal.
// Rescale needs alpha per q: 3 cndmask select + 1 shfl broadcast (only on defer-max trigger).
// LDS: K dbuf 32KB + Ps 4x2.25KB = 41KB.

__global__ __launch_bounds__(256) void k_attn(u16* __restrict__ qkv,
                                              const u16* __restrict__ Vtg) {
    __shared__ __align__(16) u16 sm[16384 + 4608];
    u16* KsB = sm;                      // [2][64*128]
    const int tid = threadIdx.x;
    const int wave = tid >> 6, lane = tid & 63;
    const int g = lane >> 4, lr = lane & 15;
    u16* Ps = sm + 16384 + wave * 1152; // [16][72] per wave

    int id = blockIdx.y * 8 + blockIdx.x;
    int xcd = id & 7, slot = id >> 3;
    int nid = xcd * 64 + slot;
    int z = nid & 7, bh = nid >> 3;
    const int b = bh >> 3, h = bh & 7;

    const size_t rowb = (size_t)b * 1024;
    const int qcol = h * 96;
    const int kcol = 768 + h * 96;
    const size_t vbase = (size_t)bh * 96 * 1024;

    int kld[3];
    size_t kgo[3];
#pragma unroll
    for (int it = 0; it < 3; ++it) {
        int c = tid + it * 256;
        int r = c / 12, s = c - r * 12;
        kgo[it] = (size_t)r * 2304 + kcol + s * 8;
        kld[it] = r * 128 + ((s ^ (r & 7)) << 3);
    }
    // per-lane V base (A-fragment layout): Vtg[bh][d=16c+lr][t = kt*64 + 32kk + 8g]
    const u16* vlane = Vtg + vbase + (size_t)lr * 1024 + 8 * g;

    const short8 onesf = (short8){0x3F80, 0x3F80, 0x3F80, 0x3F80,
                                  0x3F80, 0x3F80, 0x3F80, 0x3F80};

    for (int seg = 0; seg < 2; ++seg) {
        const int qt = (seg == 0) ? z : 15 - z;
        const int q0 = qt * 64;

        short8 qf[3];
        {
            int qrow = q0 + 16 * wave + lr;
#pragma unroll
            for (int kk = 0; kk < 3; ++kk)
                qf[kk] = *(const short8*)&qkv[(rowb + qrow) * 2304 + qcol + 32 * kk + 8 * g];
        }

        float m_r[4];
        f32x4 o[7]; // o[6] = l[q] (ones-MFMA accumulator, all rows equal)
#pragma unroll
        for (int r = 0; r < 4; ++r) m_r[r] = -3e38f;
#pragma unroll
        for (int c = 0; c < 7; ++c) o[c] = (f32x4){0.f, 0.f, 0.f, 0.f};

        u32x4 rk[3];
        short8 vf[6][2];
        // prologue: K0 -> Ks[0], K1 -> Ks[1] (if qt>0); V fragments of tile 0 -> regs
#pragma unroll
        for (int it = 0; it < 3; ++it)
            rk[it] = *(const u32x4*)&qkv[rowb * 2304 + kgo[it]];
#pragma unroll
        for (int it = 0; it < 3; ++it)
            *(u32x4*)&KsB[kld[it]] = rk[it];
        if (qt > 0) {
#pragma unroll
            for (int it = 0; it < 3; ++it)
                rk[it] = *(const u32x4*)&qkv[(rowb + 64) * 2304 + kgo[it]];
#pragma unroll
            for (int it = 0; it < 3; ++it)
                *(u32x4*)&KsB[8192 + kld[it]] = rk[it];
        }
#pragma unroll
        for (int c = 0; c < 6; ++c)
#pragma unroll
            for (int kk = 0; kk < 2; ++kk)
                vf[c][kk] = *(const short8*)&vlane[c * 16384 + 32 * kk];
        __syncthreads();

        // QK(0) -> s4a
        f32x4 s4a[4], s4b[4];
        __builtin_amdgcn_s_setprio(1);
#pragma unroll
        for (int j = 0; j < 4; ++j) {
            s4a[j] = (f32x4){0.f, 0.f, 0.f, 0.f};
#pragma unroll
            for (int kk = 0; kk < 3; ++kk) {
                short8 kf = *(const short8*)&KsB[(16 * j + lr) * 128 +
                                                (((4 * kk + g) ^ (lr & 7)) << 3)];
                s4a[j] = MFMA16(qf[kk], kf, s4a[j]);
            }
        }
        __builtin_amdgcn_s_setprio(0);

        for (int kt = 0; kt <= qt; ++kt) {
            const int cur = kt & 1;
            const bool pf2 = (kt + 2) <= qt;
            if (pf2) { // issue K loads for tile kt+2
                const size_t nkoff = (rowb + (size_t)(kt + 2) * 64) * 2304;
#pragma unroll
                for (int it = 0; it < 3; ++it)
                    rk[it] = *(const u32x4*)&qkv[nkoff + kgo[it]];
            }

            // QK(kt+1) from Ks[cur^1] (MFMA pipe) -- overlaps softmax(kt) (VALU pipe)
            if (kt < qt) {
                const u16* Ksn = KsB + (cur ^ 1) * 8192;
                __builtin_amdgcn_s_setprio(1);
#pragma unroll
                for (int j = 0; j < 4; ++j) {
                    s4b[j] = (f32x4){0.f, 0.f, 0.f, 0.f};
#pragma unroll
                    for (int kk = 0; kk < 3; ++kk) {
                        short8 kf = *(const short8*)&Ksn[(16 * j + lr) * 128 +
                                                         (((4 * kk + g) ^ (lr & 7)) << 3)];
                        s4b[j] = MFMA16(qf[kk], kf, s4b[j]);
                    }
                }
                __builtin_amdgcn_s_setprio(0);
            }

            if (kt == qt) { // diagonal mask
#pragma unroll
                for (int j = 0; j < 4; ++j) {
                    int lc = 16 * j + lr;
#pragma unroll
                    for (int r = 0; r < 4; ++r) {
                        int lrow = 16 * wave + 4 * g + r;
                        if (lc > lrow) s4a[j][r] = -3e38f;
                    }
                }
            }

            // defer-max online softmax (rows 4g+r); rescale O^T via per-q alpha broadcast
            int cl = 1;
#pragma unroll
            for (int j = 0; j < 4; ++j)
#pragma unroll
                for (int r = 0; r < 4; ++r)
                    cl &= (s4a[j][r] <= m_r[r] + 11.0f);
            if (!__all(cl)) {
                float a0, a1, a2, a3;
                {
                    float mx, mn;
#define ROWMAX(RR, AV)                                                              \
                    mx = fmaxf(fmaxf(s4a[0][RR], s4a[1][RR]),                       \
                               fmaxf(s4a[2][RR], s4a[3][RR]));                      \
                    _Pragma("unroll") for (int off = 1; off < 16; off <<= 1)        \
                        mx = fmaxf(mx, __shfl_xor(mx, off, 64));                    \
                    mn = fmaxf(m_r[RR], mx);                                        \
                    AV = exp2f(m_r[RR] - mn);                                       \
                    m_r[RR] = mn;
                    ROWMAX(0, a0) ROWMAX(1, a1) ROWMAX(2, a2) ROWMAX(3, a3)
#undef ROWMAX
                }
                // alpha for row q=lr: held as a[lr&3] by lanes with g = lr>>2
                float sel = (lr & 2) ? ((lr & 1) ? a3 : a2) : ((lr & 1) ? a1 : a0);
                float alq = __shfl(sel, ((lr >> 2) << 4) | lr, 64);
#pragma unroll
                for (int c = 0; c < 7; ++c)
#pragma unroll
                    for (int r = 0; r < 4; ++r) o[c][r] *= alq;
            }
#pragma unroll
            for (int j = 0; j < 4; ++j)
#pragma unroll
                for (int r = 0; r < 4; ++r)
                    Ps[(4 * g + r) * 72 + 16 * j + lr] = f2bf_up(exp2f(s4a[j][r] - m_r[r]));

            // PV(kt) swapped: o^T += vf (A=V^T) x pfr (B=P^T); l via ones
            short8 pfr[2];
#pragma unroll
            for (int kk = 0; kk < 2; ++kk)
                pfr[kk] = *(const short8*)&Ps[lr * 72 + 32 * kk + 8 * g];
            __builtin_amdgcn_s_setprio(1);
#pragma unroll
            for (int c = 0; c < 6; ++c) {
#pragma unroll
                for (int kk = 0; kk < 2; ++kk)
                    o[c] = MFMA16(vf[c][kk], pfr[kk], o[c]);
            }
            o[6] = MFMA16(onesf, pfr[0], o[6]);
            o[6] = MFMA16(onesf, pfr[1], o[6]);
            __builtin_amdgcn_s_setprio(0);

            // reload V fragments for tile kt+1 (consumed next phase after barrier+QK+softmax)
            if (kt < qt) {
                const int nt = (kt + 1) * 64;
#pragma unroll
                for (int c = 0; c < 6; ++c)
#pragma unroll
                    for (int kk = 0; kk < 2; ++kk)
                        vf[c][kk] = *(const short8*)&vlane[c * 16384 + nt + 32 * kk];
            }

            if (pf2) { // K write-late: tile kt+2 -> Ks[cur] (readers done at prev barrier)
#pragma unroll
                for (int it = 0; it < 3; ++it)
                    *(u32x4*)&KsB[cur * 8192 + kld[it]] = rk[it];
            }
            __syncthreads();

#pragma unroll
            for (int j = 0; j < 4; ++j) s4a[j] = s4b[j];
        }

        // epilogue O^T: lane holds O[q = q0+16*wave+lr][d = 16c+4g+r], l = o[6][0]
        {
            float inv = 1.0f / o[6][0];
            size_t rowoff = (rowb + q0 + 16 * wave + lr) * 2304 + qcol;
#pragma unroll
            for (int c = 0; c < 6; ++c) {
                u16x4 y;
#pragma unroll
                for (int r = 0; r < 4; ++r) y[r] = f2bf(o[c][r] * inv);
                *(u16x4*)&qkv[rowoff + 16 * c + 4 * g] = y;
            }
        }
        __syncthreads();
    }
}

// ---------------- GEMM2: 64x128 tile, 3 blocks/CU, one full residency round ----------------

__global__ __launch_bounds__(256, 3) void k_gemm_out(const u16* __restrict__ A,   // qkv, stride 2304
                                                     const u16* __restrict__ BT,  // [768][768]
                                                     const float* __restrict__ bias,
                                                     float* __restrict__ out) {
    __shared__ __align__(16) u16 lds[2 * 12288];
    const int tid = threadIdx.x;
    int id = blockIdx.x;                        // 768 blocks
    int nid = (id & 7) * 96 + (id >> 3);        // XCD-chunked remap (768 % 8 == 0)
    int by = nid / 6, bx = nid - by * 6;
    const int m0 = by * 64, n0 = bx * 128;

    const u16* Asrc = A + (size_t)m0 * 2304;
    const u16* Bsrc = BT + (size_t)n0 * 768;

    const int lane = tid & 63, wave = tid >> 6;
    const int wr = wave >> 1, wc = wave & 1;
    const int g = lane >> 4, lr = lane & 15;

    f32x4 acc[2][4];
#pragma unroll
    for (int i = 0; i < 2; ++i)
#pragma unroll
        for (int j = 0; j < 4; ++j) acc[i][j] = (f32x4){0.f, 0.f, 0.f, 0.f};

#pragma unroll
    for (int it = 0; it < 2; ++it) {
        int c = tid + it * 256;
        int r = c >> 3, s = c & 7, u = s ^ (r & 7);
        gl_lds16(&Asrc[(size_t)r * 2304 + u * 8], &lds[c * 8]);
    }
#pragma unroll
    for (int it = 0; it < 4; ++it) {
        int c = tid + it * 256;
        int r = c >> 3, s = c & 7, u = s ^ (r & 7);
        gl_lds16(&Bsrc[(size_t)r * 768 + u * 8], &lds[4096 + c * 8]);
    }
    __syncthreads();

    for (int t = 0; t < 12; ++t) {
        const int cur = t & 1;
        if (t < 11) {
            const int k0 = (t + 1) * 64;
            u16* dA = &lds[(cur ^ 1) * 12288];
            u16* dB = dA + 4096;
#pragma unroll
            for (int it = 0; it < 2; ++it) {
                int c = tid + it * 256;
                int r = c >> 3, s = c & 7, u = s ^ (r & 7);
                gl_lds16(&Asrc[(size_t)r * 2304 + k0 + u * 8], &dA[c * 8]);
            }
#pragma unroll
            for (int it = 0; it < 4; ++it) {
                int c = tid + it * 256;
                int r = c >> 3, s = c & 7, u = s ^ (r & 7);
                gl_lds16(&Bsrc[(size_t)r * 768 + k0 + u * 8], &dB[c * 8]);
            }
        }
        const u16* As = &lds[cur * 12288];
        const u16* Bs = As + 4096;
#pragma unroll
        for (int kk = 0; kk < 2; ++kk) {
            const int slot = ((4 * kk + g) ^ (lr & 7)) << 3;
            short8 af[2], bfv[4];
#pragma unroll
            for (int i = 0; i < 2; ++i)
                af[i] = *(const short8*)&As[(32 * wr + 16 * i + lr) * 64 + slot];
#pragma unroll
            for (int j = 0; j < 4; ++j)
                bfv[j] = *(const short8*)&Bs[(64 * wc + 16 * j + lr) * 64 + slot];
#pragma unroll
            for (int i = 0; i < 2; ++i)
#pragma unroll
                for (int j = 0; j < 4; ++j)
                    acc[i][j] = MFMA16(af[i], bfv[j], acc[i][j]);
        }
        if (t < 11) __syncthreads();
    }

#pragma unroll
    for (int i = 0; i < 2; ++i) {
        int row = m0 + 32 * wr + 16 * i + 4 * g;
#pragma unroll
        for (int j = 0; j < 4; ++j) {
            int col = n0 + 64 * wc + 16 * j + lr;
            float bsv = bias[col];
#pragma unroll
            for (int r = 0; r < 4; ++r)
                out[(size_t)(row + r) * 768 + col] = acc[i][j][r] + bsv;
        }
    }
}

// ---------------- launch ----------------

extern "C" void kernel_launch(void* const* d_in, const int* in_sizes, int n_in,
                              void* d_out, int out_size, void* d_ws, size_t ws_size,
                              hipStream_t stream) {
    const float* x      = (const float*)d_in[0];
    const float* w_qkv  = (const float*)d_in[1];
    const float* b_qkv  = (const float*)d_in[2];
    const float* w_proj = (const float*)d_in[3];
    const float* b_proj = (const float*)d_in[4];
    float* out = (float*)d_out;

    u16* xb    = (u16*)d_ws;            // 6291456
    u16* wqkvT = xb + 6291456;          // 1769472
    u16* wpT   = wqkvT + 1769472;       // 589824
    u16* qkv   = wpT + 589824;          // 18874368  [8192][2304]
    u16* Vtg   = qkv + 18874368;        // 6291456   [bh][96][1024]

    hipFuncSetAttribute((const void*)k_gemm_qkv,
                        hipFuncAttributeMaxDynamicSharedMemorySize, 69632);

    k_cvt<<<6720, 256, 0, stream>>>(x, w_qkv, w_proj, xb, wqkvT, wpT);
    k_gemm_qkv<<<1024, 256, 69632, stream>>>(xb, wqkvT, b_qkv, qkv, Vtg);
    k_attn<<<dim3(8, 64), 256, 0, stream>>>(qkv, Vtg);
    k_gemm_out<<<768, 256, 0, stream>>>(qkv, wpT, b_proj, out);
}

// Round 18
// 105.692 us; speedup vs baseline: 1.2981x; 1.2981x over previous
//
#include <hip/hip_runtime.h>
#include <hip/hip_bf16.h>
#include <stdint.h>

typedef unsigned short u16;
typedef unsigned int u32;
typedef __attribute__((ext_vector_type(8))) short short8;
typedef __attribute__((ext_vector_type(4))) float f32x4;
typedef __attribute__((ext_vector_type(4))) unsigned int u32x4;
typedef __attribute__((ext_vector_type(4))) unsigned short u16x4;

#define MFMA16(a, b, c) __builtin_amdgcn_mfma_f32_16x16x32_bf16((a), (b), (c), 0, 0, 0)

__device__ __forceinline__ u16 f2bf(float f) {
    union { float f; uint32_t u; } v; v.f = f;
    return (u16)((v.u + 0x7FFFu + ((v.u >> 16) & 1u)) >> 16);
}
__device__ __forceinline__ u16 f2bf_up(float f) {  // round-half-up, f >= 0
    union { float f; uint32_t u; } v; v.f = f;
    return (u16)((v.u + 0x8000u) >> 16);
}

// async global -> LDS, 16 bytes per lane (dest must be linear: base + lane*16)
__device__ __forceinline__ void gl_lds16(const u16* g, u16* l) {
    __builtin_amdgcn_global_load_lds(
        (const __attribute__((address_space(1))) u32*)g,
        (__attribute__((address_space(3))) u32*)l,
        16, 0, 0);
}

// ---------------- merged convert kernel (one launch) ----------------

__global__ __launch_bounds__(256) void k_cvt(const float* __restrict__ x,
                                             const float* __restrict__ wq,
                                             const float* __restrict__ wp,
                                             u16* __restrict__ xb,
                                             u16* __restrict__ outq,
                                             u16* __restrict__ outp) {
    __shared__ u16 t[64][72];
    if (blockIdx.x < 6144) {
        int i = (blockIdx.x * 256 + threadIdx.x) * 4;
        f32x4 v = *(const f32x4*)(x + i);
        u16x4 o;
        o[0] = f2bf(v[0]); o[1] = f2bf(v[1]); o[2] = f2bf(v[2]); o[3] = f2bf(v[3]);
        *(u16x4*)(xb + i) = o;
        return;
    }
    int bid = blockIdx.x - 6144;          // 0..575
    int bx = bid % 48, kb = (bid / 48) * 64;
    const float* in; u16* out; int N, nb;
    if (bx < 36) { in = wq; out = outq; N = 2304; nb = bx * 64; }
    else         { in = wp; out = outp; N = 768;  nb = (bx - 36) * 64; }
    const int tid = threadIdx.x;
    const int r = tid >> 4, c4 = (tid & 15) << 2;
#pragma unroll
    for (int p = 0; p < 4; ++p) {
        int k = r + p * 16;
        f32x4 v = *(const f32x4*)&in[(size_t)(kb + k) * N + nb + c4];
#pragma unroll
        for (int q = 0; q < 4; ++q) t[c4 + q][k] = f2bf(v[q]);
    }
    __syncthreads();
#pragma unroll
    for (int p = 0; p < 4; ++p) {
        int nn = r + p * 16;
        u16x4 o;
#pragma unroll
        for (int q = 0; q < 4; ++q) o[q] = t[nn][c4 + q];
        *(u16x4*)&out[(size_t)(nb + nn) * 768 + kb + c4] = o;
    }
}

// ---------------- GEMM1: 64x128 tile, 3 blocks/CU, grid 2304 = exactly 3 rounds ----------------
// Geometry cloned from k_gemm_out (measured 1123 TF effective): 48KB LDS dbuf, BK=64,
// cross-block overlap (m114) hides the 2-phase barrier drain.
// Q (cols<768, pre-scaled by 1/sqrt(96)*log2e) and K -> qkv rows; V -> Vtg[bh][d][t].

__global__ __launch_bounds__(256, 3) void k_gemm_qkv(const u16* __restrict__ A,
                                                     const u16* __restrict__ BT,
                                                     const float* __restrict__ bias,
                                                     u16* __restrict__ qkv,
                                                     u16* __restrict__ Vtg) {
    __shared__ __align__(16) u16 lds[2 * 12288];
    const int tid = threadIdx.x;
    int id = blockIdx.x;                        // 2304 blocks
    int nid = (id & 7) * 288 + (id >> 3);       // XCD-chunked remap (2304 % 8 == 0)
    int by = nid / 18, bx = nid - by * 18;
    const int m0 = by * 64, n0 = bx * 128;

    const u16* Asrc = A + (size_t)m0 * 768;
    const u16* Bsrc = BT + (size_t)n0 * 768;

    const int lane = tid & 63, wave = tid >> 6;
    const int wr = wave >> 1, wc = wave & 1;
    const int g = lane >> 4, lr = lane & 15;

    f32x4 acc[2][4];
#pragma unroll
    for (int i = 0; i < 2; ++i)
#pragma unroll
        for (int j = 0; j < 4; ++j) acc[i][j] = (f32x4){0.f, 0.f, 0.f, 0.f};

    // prologue: stage tile 0 into buf0
#pragma unroll
    for (int it = 0; it < 2; ++it) {            // A: 512 chunks
        int c = tid + it * 256;
        int r = c >> 3, s = c & 7, u = s ^ (r & 7);
        gl_lds16(&Asrc[(size_t)r * 768 + u * 8], &lds[c * 8]);
    }
#pragma unroll
    for (int it = 0; it < 4; ++it) {            // B: 1024 chunks
        int c = tid + it * 256;
        int r = c >> 3, s = c & 7, u = s ^ (r & 7);
        gl_lds16(&Bsrc[(size_t)r * 768 + u * 8], &lds[4096 + c * 8]);
    }
    __syncthreads();

    for (int t = 0; t < 12; ++t) {
        const int cur = t & 1;
        if (t < 11) {
            const int k0 = (t + 1) * 64;
            u16* dA = &lds[(cur ^ 1) * 12288];
            u16* dB = dA + 4096;
#pragma unroll
            for (int it = 0; it < 2; ++it) {
                int c = tid + it * 256;
                int r = c >> 3, s = c & 7, u = s ^ (r & 7);
                gl_lds16(&Asrc[(size_t)r * 768 + k0 + u * 8], &dA[c * 8]);
            }
#pragma unroll
            for (int it = 0; it < 4; ++it) {
                int c = tid + it * 256;
                int r = c >> 3, s = c & 7, u = s ^ (r & 7);
                gl_lds16(&Bsrc[(size_t)r * 768 + k0 + u * 8], &dB[c * 8]);
            }
        }
        const u16* As = &lds[cur * 12288];
        const u16* Bs = As + 4096;
#pragma unroll
        for (int kk = 0; kk < 2; ++kk) {
            const int slot = ((4 * kk + g) ^ (lr & 7)) << 3;
            short8 af[2], bfv[4];
#pragma unroll
            for (int i = 0; i < 2; ++i)
                af[i] = *(const short8*)&As[(32 * wr + 16 * i + lr) * 64 + slot];
#pragma unroll
            for (int j = 0; j < 4; ++j)
                bfv[j] = *(const short8*)&Bs[(64 * wc + 16 * j + lr) * 64 + slot];
#pragma unroll
            for (int i = 0; i < 2; ++i)
#pragma unroll
                for (int j = 0; j < 4; ++j)
                    acc[i][j] = MFMA16(af[i], bfv[j], acc[i][j]);
        }
        if (t < 11) __syncthreads();
    }

    const float CS = 0.14724449f; // 1/sqrt(96) * log2(e)
#pragma unroll
    for (int i = 0; i < 2; ++i) {
        int row = m0 + 32 * wr + 16 * i + 4 * g;
#pragma unroll
        for (int j = 0; j < 4; ++j) {
            int col = n0 + 64 * wc + 16 * j + lr;
            float bsv = bias[col];
            if (col < 1536) {
                float sc = (col < 768) ? CS : 1.0f;
#pragma unroll
                for (int r = 0; r < 4; ++r)
                    qkv[(size_t)(row + r) * 2304 + col] = f2bf((acc[i][j][r] + bsv) * sc);
            } else {
                int jj = col - 1536;
                int h = jj / 96, d = jj - h * 96;
                int t2 = row & 1023, bb = row >> 10;
                int bh = bb * 8 + h;
                u16x4 vv;
#pragma unroll
                for (int r = 0; r < 4; ++r) vv[r] = f2bf(acc[i][j][r] + bsv);
                *(u16x4*)&Vtg[((size_t)bh * 96 + d) * 1024 + t2] = vv;
            }
        }
    }
}

// ---------------- flash attention (r15 proven: pipelined QK, V 3-slot, 41.7us) ----------------

__global__ __launch_bounds__(256) void k_attn(u16* __restrict__ qkv,
                                              const u16* __restrict__ Vtg) {
    __shared__ __align__(16) u16 sm[16384 + 18432 + 4608];
    u16* KsB = sm;                      // [2][64*128]
    u16* VtB = sm + 16384;              // [3][96*64]
    const int tid = threadIdx.x;
    const int wave = tid >> 6, lane = tid & 63;
    const int g = lane >> 4, lr = lane & 15;
    u16* Ps = sm + 16384 + 18432 + wave * 1152;   // [16][72]

    int id = blockIdx.y * 8 + blockIdx.x;
    int xcd = id & 7, slot = id >> 3;
    int nid = xcd * 64 + slot;
    int z = nid & 7, bh = nid >> 3;
    const int b = bh >> 3, h = bh & 7;

    const size_t rowb = (size_t)b * 1024;
    const int qcol = h * 96;
    const int kcol = 768 + h * 96;
    const size_t vbase = (size_t)bh * 96 * 1024;

    int kld[3], vld[3];
    size_t kgo[3], vgo[3];
#pragma unroll
    for (int it = 0; it < 3; ++it) {
        int c = tid + it * 256;
        int r = c / 12, s = c - r * 12;
        kgo[it] = (size_t)r * 2304 + kcol + s * 8;
        kld[it] = r * 128 + ((s ^ (r & 7)) << 3);
        int vr = c >> 3, vs = c & 7;
        vgo[it] = (size_t)vr * 1024 + vs * 8;
        vld[it] = vr * 64 + ((vs ^ (vr & 7)) << 3);
    }

    const short8 onesf = (short8){0x3F80, 0x3F80, 0x3F80, 0x3F80,
                                  0x3F80, 0x3F80, 0x3F80, 0x3F80};

    for (int seg = 0; seg < 2; ++seg) {
        const int qt = (seg == 0) ? z : 15 - z;
        const int q0 = qt * 64;

        short8 qf[3];
        {
            int qrow = q0 + 16 * wave + lr;
#pragma unroll
            for (int kk = 0; kk < 3; ++kk)
                qf[kk] = *(const short8*)&qkv[(rowb + qrow) * 2304 + qcol + 32 * kk + 8 * g];
        }

        float m_r[4];
        f32x4 o[7]; // o[6] = l (ones-MFMA accumulator)
#pragma unroll
        for (int r = 0; r < 4; ++r) m_r[r] = -3e38f;
#pragma unroll
        for (int c = 0; c < 7; ++c) o[c] = (f32x4){0.f, 0.f, 0.f, 0.f};

        u32x4 rk[3], rv[3];
        // prologue: stage tile 0 (and tile 1 if present)
#pragma unroll
        for (int it = 0; it < 3; ++it) {
            rk[it] = *(const u32x4*)&qkv[rowb * 2304 + kgo[it]];
            rv[it] = *(const u32x4*)&Vtg[vbase + vgo[it]];
        }
#pragma unroll
        for (int it = 0; it < 3; ++it) {
            *(u32x4*)&KsB[kld[it]] = rk[it];
            *(u32x4*)&VtB[vld[it]] = rv[it];
        }
        if (qt > 0) {
#pragma unroll
            for (int it = 0; it < 3; ++it) {
                rk[it] = *(const u32x4*)&qkv[(rowb + 64) * 2304 + kgo[it]];
                rv[it] = *(const u32x4*)&Vtg[vbase + 64 + vgo[it]];
            }
#pragma unroll
            for (int it = 0; it < 3; ++it) {
                *(u32x4*)&KsB[8192 + kld[it]] = rk[it];
                *(u32x4*)&VtB[6144 + vld[it]] = rv[it];
            }
        }
        __syncthreads();

        // QK(0) -> s4a
        f32x4 s4a[4], s4b[4];
        __builtin_amdgcn_s_setprio(1);
#pragma unroll
        for (int j = 0; j < 4; ++j) {
            s4a[j] = (f32x4){0.f, 0.f, 0.f, 0.f};
#pragma unroll
            for (int kk = 0; kk < 3; ++kk) {
                short8 kf = *(const short8*)&KsB[(16 * j + lr) * 128 +
                                                (((4 * kk + g) ^ (lr & 7)) << 3)];
                s4a[j] = MFMA16(qf[kk], kf, s4a[j]);
            }
        }
        __builtin_amdgcn_s_setprio(0);

        int vcur = 0; // V slot of tile kt
        for (int kt = 0; kt <= qt; ++kt) {
            const int cur = kt & 1;
            const int vwr = (vcur == 0) ? 2 : vcur - 1; // slot (kt+2)%3
            const bool pf2 = (kt + 2) <= qt;
            if (pf2) { // issue loads for tile kt+2
                const size_t nkoff = (rowb + (size_t)(kt + 2) * 64) * 2304;
                const size_t nv = vbase + (size_t)(kt + 2) * 64;
#pragma unroll
                for (int it = 0; it < 3; ++it) {
                    rk[it] = *(const u32x4*)&qkv[nkoff + kgo[it]];
                    rv[it] = *(const u32x4*)&Vtg[nv + vgo[it]];
                }
            }

            // QK(kt+1) from Ks[cur^1] (MFMA pipe) -- overlaps softmax(kt) (VALU pipe)
            if (kt < qt) {
                const u16* Ksn = KsB + (cur ^ 1) * 8192;
                __builtin_amdgcn_s_setprio(1);
#pragma unroll
                for (int j = 0; j < 4; ++j) {
                    s4b[j] = (f32x4){0.f, 0.f, 0.f, 0.f};
#pragma unroll
                    for (int kk = 0; kk < 3; ++kk) {
                        short8 kf = *(const short8*)&Ksn[(16 * j + lr) * 128 +
                                                         (((4 * kk + g) ^ (lr & 7)) << 3)];
                        s4b[j] = MFMA16(qf[kk], kf, s4b[j]);
                    }
                }
                __builtin_amdgcn_s_setprio(0);
            }

            if (kt == qt) { // diagonal mask
#pragma unroll
                for (int j = 0; j < 4; ++j) {
                    int lc = 16 * j + lr;
#pragma unroll
                    for (int r = 0; r < 4; ++r) {
                        int lrow = 16 * wave + 4 * g + r;
                        if (lc > lrow) s4a[j][r] = -3e38f;
                    }
                }
            }

            // defer-max online softmax
            int cl = 1;
#pragma unroll
            for (int j = 0; j < 4; ++j)
#pragma unroll
                for (int r = 0; r < 4; ++r)
                    cl &= (s4a[j][r] <= m_r[r] + 11.0f);
            if (!__all(cl)) {
#pragma unroll
                for (int r = 0; r < 4; ++r) {
                    float mx = fmaxf(fmaxf(s4a[0][r], s4a[1][r]), fmaxf(s4a[2][r], s4a[3][r]));
#pragma unroll
                    for (int off = 1; off < 16; off <<= 1)
                        mx = fmaxf(mx, __shfl_xor(mx, off, 64));
                    float mn = fmaxf(m_r[r], mx);
                    float a = exp2f(m_r[r] - mn);
                    m_r[r] = mn;
#pragma unroll
                    for (int c = 0; c < 7; ++c) o[c][r] *= a;
                }
            }
#pragma unroll
            for (int j = 0; j < 4; ++j)
#pragma unroll
                for (int r = 0; r < 4; ++r)
                    Ps[(4 * g + r) * 72 + 16 * j + lr] = f2bf_up(exp2f(s4a[j][r] - m_r[r]));

            // PV(kt) + l (ones fragment); V from slot vcur
            const u16* Vt = VtB + vcur * 6144;
            short8 pfr[2];
#pragma unroll
            for (int kk = 0; kk < 2; ++kk)
                pfr[kk] = *(const short8*)&Ps[lr * 72 + 32 * kk + 8 * g];
            __builtin_amdgcn_s_setprio(1);
#pragma unroll
            for (int c = 0; c < 6; ++c) {
#pragma unroll
                for (int kk = 0; kk < 2; ++kk) {
                    short8 vf = *(const short8*)&Vt[(16 * c + lr) * 64 +
                                                    (((4 * kk + g) ^ (lr & 7)) << 3)];
                    o[c] = MFMA16(pfr[kk], vf, o[c]);
                }
            }
            o[6] = MFMA16(pfr[0], onesf, o[6]);
            o[6] = MFMA16(pfr[1], onesf, o[6]);
            __builtin_amdgcn_s_setprio(0);

            if (pf2) { // write tile kt+2: Ks[cur], Vt[vwr]
#pragma unroll
                for (int it = 0; it < 3; ++it) {
                    *(u32x4*)&KsB[cur * 8192 + kld[it]] = rk[it];
                    *(u32x4*)&VtB[vwr * 6144 + vld[it]] = rv[it];
                }
            }
            __syncthreads();

#pragma unroll
            for (int j = 0; j < 4; ++j) s4a[j] = s4b[j];
            vcur = (vcur == 2) ? 0 : vcur + 1;
        }

        // epilogue: write Y into qkv Q region
#pragma unroll
        for (int r = 0; r < 4; ++r) {
            int t = q0 + 16 * wave + 4 * g + r;
            float inv = 1.0f / o[6][r];
            size_t rowoff = (rowb + t) * 2304 + qcol;
#pragma unroll
            for (int c = 0; c < 6; ++c)
                qkv[rowoff + 16 * c + lr] = f2bf(o[c][r] * inv);
        }
        __syncthreads();
    }
}

// ---------------- GEMM2: 64x128 tile, 3 blocks/CU, one full residency round ----------------

__global__ __launch_bounds__(256, 3) void k_gemm_out(const u16* __restrict__ A,   // qkv, stride 2304
                                                     const u16* __restrict__ BT,  // [768][768]
                                                     const float* __restrict__ bias,
                                                     float* __restrict__ out) {
    __shared__ __align__(16) u16 lds[2 * 12288];
    const int tid = threadIdx.x;
    int id = blockIdx.x;                        // 768 blocks
    int nid = (id & 7) * 96 + (id >> 3);        // XCD-chunked remap (768 % 8 == 0)
    int by = nid / 6, bx = nid - by * 6;
    const int m0 = by * 64, n0 = bx * 128;

    const u16* Asrc = A + (size_t)m0 * 2304;
    const u16* Bsrc = BT + (size_t)n0 * 768;

    const int lane = tid & 63, wave = tid >> 6;
    const int wr = wave >> 1, wc = wave & 1;
    const int g = lane >> 4, lr = lane & 15;

    f32x4 acc[2][4];
#pragma unroll
    for (int i = 0; i < 2; ++i)
#pragma unroll
        for (int j = 0; j < 4; ++j) acc[i][j] = (f32x4){0.f, 0.f, 0.f, 0.f};

#pragma unroll
    for (int it = 0; it < 2; ++it) {
        int c = tid + it * 256;
        int r = c >> 3, s = c & 7, u = s ^ (r & 7);
        gl_lds16(&Asrc[(size_t)r * 2304 + u * 8], &lds[c * 8]);
    }
#pragma unroll
    for (int it = 0; it < 4; ++it) {
        int c = tid + it * 256;
        int r = c >> 3, s = c & 7, u = s ^ (r & 7);
        gl_lds16(&Bsrc[(size_t)r * 768 + u * 8], &lds[4096 + c * 8]);
    }
    __syncthreads();

    for (int t = 0; t < 12; ++t) {
        const int cur = t & 1;
        if (t < 11) {
            const int k0 = (t + 1) * 64;
            u16* dA = &lds[(cur ^ 1) * 12288];
            u16* dB = dA + 4096;
#pragma unroll
            for (int it = 0; it < 2; ++it) {
                int c = tid + it * 256;
                int r = c >> 3, s = c & 7, u = s ^ (r & 7);
                gl_lds16(&Asrc[(size_t)r * 2304 + k0 + u * 8], &dA[c * 8]);
            }
#pragma unroll
            for (int it = 0; it < 4; ++it) {
                int c = tid + it * 256;
                int r = c >> 3, s = c & 7, u = s ^ (r & 7);
                gl_lds16(&Bsrc[(size_t)r * 768 + k0 + u * 8], &dB[c * 8]);
            }
        }
        const u16* As = &lds[cur * 12288];
        const u16* Bs = As + 4096;
#pragma unroll
        for (int kk = 0; kk < 2; ++kk) {
            const int slot = ((4 * kk + g) ^ (lr & 7)) << 3;
            short8 af[2], bfv[4];
#pragma unroll
            for (int i = 0; i < 2; ++i)
                af[i] = *(const short8*)&As[(32 * wr + 16 * i + lr) * 64 + slot];
#pragma unroll
            for (int j = 0; j < 4; ++j)
                bfv[j] = *(const short8*)&Bs[(64 * wc + 16 * j + lr) * 64 + slot];
#pragma unroll
            for (int i = 0; i < 2; ++i)
#pragma unroll
                for (int j = 0; j < 4; ++j)
                    acc[i][j] = MFMA16(af[i], bfv[j], acc[i][j]);
        }
        if (t < 11) __syncthreads();
    }

#pragma unroll
    for (int i = 0; i < 2; ++i) {
        int row = m0 + 32 * wr + 16 * i + 4 * g;
#pragma unroll
        for (int j = 0; j < 4; ++j) {
            int col = n0 + 64 * wc + 16 * j + lr;
            float bsv = bias[col];
#pragma unroll
            for (int r = 0; r < 4; ++r)
                out[(size_t)(row + r) * 768 + col] = acc[i][j][r] + bsv;
        }
    }
}

// ---------------- launch ----------------

extern "C" void kernel_launch(void* const* d_in, const int* in_sizes, int n_in,
                              void* d_out, int out_size, void* d_ws, size_t ws_size,
                              hipStream_t stream) {
    const float* x      = (const float*)d_in[0];
    const float* w_qkv  = (const float*)d_in[1];
    const float* b_qkv  = (const float*)d_in[2];
    const float* w_proj = (const float*)d_in[3];
    const float* b_proj = (const float*)d_in[4];
    float* out = (float*)d_out;

    u16* xb    = (u16*)d_ws;            // 6291456
    u16* wqkvT = xb + 6291456;          // 1769472
    u16* wpT   = wqkvT + 1769472;       // 589824
    u16* qkv   = wpT + 589824;          // 18874368  [8192][2304]
    u16* Vtg   = qkv + 18874368;        // 6291456   [bh][96][1024]

    k_cvt<<<6720, 256, 0, stream>>>(x, w_qkv, w_proj, xb, wqkvT, wpT);
    k_gemm_qkv<<<2304, 256, 0, stream>>>(xb, wqkvT, b_qkv, qkv, Vtg);
    k_attn<<<dim3(8, 64), 256, 0, stream>>>(qkv, Vtg);
    k_gemm_out<<<768, 256, 0, stream>>>(qkv, wpT, b_proj, out);
}

// Round 19
// 105.551 us; speedup vs baseline: 1.2999x; 1.0013x over previous
//
#include <hip/hip_runtime.h>
#include <hip/hip_bf16.h>
#include <stdint.h>

typedef unsigned short u16;
typedef unsigned int u32;
typedef __attribute__((ext_vector_type(8))) short short8;
typedef __attribute__((ext_vector_type(4))) float f32x4;
typedef __attribute__((ext_vector_type(4))) unsigned int u32x4;
typedef __attribute__((ext_vector_type(4))) unsigned short u16x4;

#define MFMA16(a, b, c) __builtin_amdgcn_mfma_f32_16x16x32_bf16((a), (b), (c), 0, 0, 0)

__device__ __forceinline__ u16 f2bf(float f) {
    union { float f; uint32_t u; } v; v.f = f;
    return (u16)((v.u + 0x7FFFu + ((v.u >> 16) & 1u)) >> 16);
}
__device__ __forceinline__ u16 f2bf_up(float f) {  // round-half-up, f >= 0
    union { float f; uint32_t u; } v; v.f = f;
    return (u16)((v.u + 0x8000u) >> 16);
}

// async global -> LDS, 16 bytes per lane (dest must be linear: base + lane*16)
__device__ __forceinline__ void gl_lds16(const u16* g, u16* l) {
    __builtin_amdgcn_global_load_lds(
        (const __attribute__((address_space(1))) u32*)g,
        (__attribute__((address_space(3))) u32*)l,
        16, 0, 0);
}

// ---------------- merged convert kernel (one launch) ----------------

__global__ __launch_bounds__(256) void k_cvt(const float* __restrict__ x,
                                             const float* __restrict__ wq,
                                             const float* __restrict__ wp,
                                             u16* __restrict__ xb,
                                             u16* __restrict__ outq,
                                             u16* __restrict__ outp) {
    __shared__ u16 t[64][72];
    if (blockIdx.x < 6144) {
        int i = (blockIdx.x * 256 + threadIdx.x) * 4;
        f32x4 v = *(const f32x4*)(x + i);
        u16x4 o;
        o[0] = f2bf(v[0]); o[1] = f2bf(v[1]); o[2] = f2bf(v[2]); o[3] = f2bf(v[3]);
        *(u16x4*)(xb + i) = o;
        return;
    }
    int bid = blockIdx.x - 6144;          // 0..575
    int bx = bid % 48, kb = (bid / 48) * 64;
    const float* in; u16* out; int N, nb;
    if (bx < 36) { in = wq; out = outq; N = 2304; nb = bx * 64; }
    else         { in = wp; out = outp; N = 768;  nb = (bx - 36) * 64; }
    const int tid = threadIdx.x;
    const int r = tid >> 4, c4 = (tid & 15) << 2;
#pragma unroll
    for (int p = 0; p < 4; ++p) {
        int k = r + p * 16;
        f32x4 v = *(const f32x4*)&in[(size_t)(kb + k) * N + nb + c4];
#pragma unroll
        for (int q = 0; q < 4; ++q) t[c4 + q][k] = f2bf(v[q]);
    }
    __syncthreads();
#pragma unroll
    for (int p = 0; p < 4; ++p) {
        int nn = r + p * 16;
        u16x4 o;
#pragma unroll
        for (int q = 0; q < 4; ++q) o[q] = t[nn][c4 + q];
        *(u16x4*)&out[(size_t)(nb + nn) * 768 + kb + c4] = o;
    }
}

// ---------------- GEMM1: 64x128 tile, 3 blocks/CU, grid 2304 = exactly 3 rounds ----------------
// Block order: bx-SLOW within each XCD. Each XCD owns a private 16-row A slab (1.5MB,
// hot all kernel) and sweeps B one 196KB tile per 16 blocks -> concurrent L2 working set
// ~1.7MB << 4MB (fixes the 48MB over-fetch measured in r18).
// Q (cols<768, pre-scaled by 1/sqrt(96)*log2e) and K -> qkv rows; V -> Vtg[bh][d][t].

__global__ __launch_bounds__(256, 3) void k_gemm_qkv(const u16* __restrict__ A,
                                                     const u16* __restrict__ BT,
                                                     const float* __restrict__ bias,
                                                     u16* __restrict__ qkv,
                                                     u16* __restrict__ Vtg) {
    __shared__ __align__(16) u16 lds[2 * 12288];
    const int tid = threadIdx.x;
    int id = blockIdx.x;                        // 2304 blocks
    int local = id >> 3, xcd = id & 7;
    int bx = local >> 4;                        // 0..17, changes every 16 blocks
    int by = (xcd << 4) | (local & 15);         // XCD-private 16-row slab
    const int m0 = by * 64, n0 = bx * 128;

    const u16* Asrc = A + (size_t)m0 * 768;
    const u16* Bsrc = BT + (size_t)n0 * 768;

    const int lane = tid & 63, wave = tid >> 6;
    const int wr = wave >> 1, wc = wave & 1;
    const int g = lane >> 4, lr = lane & 15;

    f32x4 acc[2][4];
#pragma unroll
    for (int i = 0; i < 2; ++i)
#pragma unroll
        for (int j = 0; j < 4; ++j) acc[i][j] = (f32x4){0.f, 0.f, 0.f, 0.f};

    // prologue: stage tile 0 into buf0
#pragma unroll
    for (int it = 0; it < 2; ++it) {            // A: 512 chunks
        int c = tid + it * 256;
        int r = c >> 3, s = c & 7, u = s ^ (r & 7);
        gl_lds16(&Asrc[(size_t)r * 768 + u * 8], &lds[c * 8]);
    }
#pragma unroll
    for (int it = 0; it < 4; ++it) {            // B: 1024 chunks
        int c = tid + it * 256;
        int r = c >> 3, s = c & 7, u = s ^ (r & 7);
        gl_lds16(&Bsrc[(size_t)r * 768 + u * 8], &lds[4096 + c * 8]);
    }
    __syncthreads();

    for (int t = 0; t < 12; ++t) {
        const int cur = t & 1;
        if (t < 11) {
            const int k0 = (t + 1) * 64;
            u16* dA = &lds[(cur ^ 1) * 12288];
            u16* dB = dA + 4096;
#pragma unroll
            for (int it = 0; it < 2; ++it) {
                int c = tid + it * 256;
                int r = c >> 3, s = c & 7, u = s ^ (r & 7);
                gl_lds16(&Asrc[(size_t)r * 768 + k0 + u * 8], &dA[c * 8]);
            }
#pragma unroll
            for (int it = 0; it < 4; ++it) {
                int c = tid + it * 256;
                int r = c >> 3, s = c & 7, u = s ^ (r & 7);
                gl_lds16(&Bsrc[(size_t)r * 768 + k0 + u * 8], &dB[c * 8]);
            }
        }
        const u16* As = &lds[cur * 12288];
        const u16* Bs = As + 4096;
#pragma unroll
        for (int kk = 0; kk < 2; ++kk) {
            const int slot = ((4 * kk + g) ^ (lr & 7)) << 3;
            short8 af[2], bfv[4];
#pragma unroll
            for (int i = 0; i < 2; ++i)
                af[i] = *(const short8*)&As[(32 * wr + 16 * i + lr) * 64 + slot];
#pragma unroll
            for (int j = 0; j < 4; ++j)
                bfv[j] = *(const short8*)&Bs[(64 * wc + 16 * j + lr) * 64 + slot];
#pragma unroll
            for (int i = 0; i < 2; ++i)
#pragma unroll
                for (int j = 0; j < 4; ++j)
                    acc[i][j] = MFMA16(af[i], bfv[j], acc[i][j]);
        }
        if (t < 11) __syncthreads();
    }

    const float CS = 0.14724449f; // 1/sqrt(96) * log2(e)
#pragma unroll
    for (int i = 0; i < 2; ++i) {
        int row = m0 + 32 * wr + 16 * i + 4 * g;
#pragma unroll
        for (int j = 0; j < 4; ++j) {
            int col = n0 + 64 * wc + 16 * j + lr;
            float bsv = bias[col];
            if (col < 1536) {
                float sc = (col < 768) ? CS : 1.0f;
#pragma unroll
                for (int r = 0; r < 4; ++r)
                    qkv[(size_t)(row + r) * 2304 + col] = f2bf((acc[i][j][r] + bsv) * sc);
            } else {
                int jj = col - 1536;
                int h = jj / 96, d = jj - h * 96;
                int t2 = row & 1023, bb = row >> 10;
                int bh = bb * 8 + h;
                u16x4 vv;
#pragma unroll
                for (int r = 0; r < 4; ++r) vv[r] = f2bf(acc[i][j][r] + bsv);
                *(u16x4*)&Vtg[((size_t)bh * 96 + d) * 1024 + t2] = vv;
            }
        }
    }
}

// ---------------- flash attention (r15 proven: pipelined QK, V 3-slot, 41.7us) ----------------

__global__ __launch_bounds__(256) void k_attn(u16* __restrict__ qkv,
                                              const u16* __restrict__ Vtg) {
    __shared__ __align__(16) u16 sm[16384 + 18432 + 4608];
    u16* KsB = sm;                      // [2][64*128]
    u16* VtB = sm + 16384;              // [3][96*64]
    const int tid = threadIdx.x;
    const int wave = tid >> 6, lane = tid & 63;
    const int g = lane >> 4, lr = lane & 15;
    u16* Ps = sm + 16384 + 18432 + wave * 1152;   // [16][72]

    int id = blockIdx.y * 8 + blockIdx.x;
    int xcd = id & 7, slot = id >> 3;
    int nid = xcd * 64 + slot;
    int z = nid & 7, bh = nid >> 3;
    const int b = bh >> 3, h = bh & 7;

    const size_t rowb = (size_t)b * 1024;
    const int qcol = h * 96;
    const int kcol = 768 + h * 96;
    const size_t vbase = (size_t)bh * 96 * 1024;

    int kld[3], vld[3];
    size_t kgo[3], vgo[3];
#pragma unroll
    for (int it = 0; it < 3; ++it) {
        int c = tid + it * 256;
        int r = c / 12, s = c - r * 12;
        kgo[it] = (size_t)r * 2304 + kcol + s * 8;
        kld[it] = r * 128 + ((s ^ (r & 7)) << 3);
        int vr = c >> 3, vs = c & 7;
        vgo[it] = (size_t)vr * 1024 + vs * 8;
        vld[it] = vr * 64 + ((vs ^ (vr & 7)) << 3);
    }

    const short8 onesf = (short8){0x3F80, 0x3F80, 0x3F80, 0x3F80,
                                  0x3F80, 0x3F80, 0x3F80, 0x3F80};

    for (int seg = 0; seg < 2; ++seg) {
        const int qt = (seg == 0) ? z : 15 - z;
        const int q0 = qt * 64;

        short8 qf[3];
        {
            int qrow = q0 + 16 * wave + lr;
#pragma unroll
            for (int kk = 0; kk < 3; ++kk)
                qf[kk] = *(const short8*)&qkv[(rowb + qrow) * 2304 + qcol + 32 * kk + 8 * g];
        }

        float m_r[4];
        f32x4 o[7]; // o[6] = l (ones-MFMA accumulator)
#pragma unroll
        for (int r = 0; r < 4; ++r) m_r[r] = -3e38f;
#pragma unroll
        for (int c = 0; c < 7; ++c) o[c] = (f32x4){0.f, 0.f, 0.f, 0.f};

        u32x4 rk[3], rv[3];
        // prologue: stage tile 0 (and tile 1 if present)
#pragma unroll
        for (int it = 0; it < 3; ++it) {
            rk[it] = *(const u32x4*)&qkv[rowb * 2304 + kgo[it]];
            rv[it] = *(const u32x4*)&Vtg[vbase + vgo[it]];
        }
#pragma unroll
        for (int it = 0; it < 3; ++it) {
            *(u32x4*)&KsB[kld[it]] = rk[it];
            *(u32x4*)&VtB[vld[it]] = rv[it];
        }
        if (qt > 0) {
#pragma unroll
            for (int it = 0; it < 3; ++it) {
                rk[it] = *(const u32x4*)&qkv[(rowb + 64) * 2304 + kgo[it]];
                rv[it] = *(const u32x4*)&Vtg[vbase + 64 + vgo[it]];
            }
#pragma unroll
            for (int it = 0; it < 3; ++it) {
                *(u32x4*)&KsB[8192 + kld[it]] = rk[it];
                *(u32x4*)&VtB[6144 + vld[it]] = rv[it];
            }
        }
        __syncthreads();

        // QK(0) -> s4a
        f32x4 s4a[4], s4b[4];
        __builtin_amdgcn_s_setprio(1);
#pragma unroll
        for (int j = 0; j < 4; ++j) {
            s4a[j] = (f32x4){0.f, 0.f, 0.f, 0.f};
#pragma unroll
            for (int kk = 0; kk < 3; ++kk) {
                short8 kf = *(const short8*)&KsB[(16 * j + lr) * 128 +
                                                (((4 * kk + g) ^ (lr & 7)) << 3)];
                s4a[j] = MFMA16(qf[kk], kf, s4a[j]);
            }
        }
        __builtin_amdgcn_s_setprio(0);

        int vcur = 0; // V slot of tile kt
        for (int kt = 0; kt <= qt; ++kt) {
            const int cur = kt & 1;
            const int vwr = (vcur == 0) ? 2 : vcur - 1; // slot (kt+2)%3
            const bool pf2 = (kt + 2) <= qt;
            if (pf2) { // issue loads for tile kt+2
                const size_t nkoff = (rowb + (size_t)(kt + 2) * 64) * 2304;
                const size_t nv = vbase + (size_t)(kt + 2) * 64;
#pragma unroll
                for (int it = 0; it < 3; ++it) {
                    rk[it] = *(const u32x4*)&qkv[nkoff + kgo[it]];
                    rv[it] = *(const u32x4*)&Vtg[nv + vgo[it]];
                }
            }

            // QK(kt+1) from Ks[cur^1] (MFMA pipe) -- overlaps softmax(kt) (VALU pipe)
            if (kt < qt) {
                const u16* Ksn = KsB + (cur ^ 1) * 8192;
                __builtin_amdgcn_s_setprio(1);
#pragma unroll
                for (int j = 0; j < 4; ++j) {
                    s4b[j] = (f32x4){0.f, 0.f, 0.f, 0.f};
#pragma unroll
                    for (int kk = 0; kk < 3; ++kk) {
                        short8 kf = *(const short8*)&Ksn[(16 * j + lr) * 128 +
                                                         (((4 * kk + g) ^ (lr & 7)) << 3)];
                        s4b[j] = MFMA16(qf[kk], kf, s4b[j]);
                    }
                }
                __builtin_amdgcn_s_setprio(0);
            }

            if (kt == qt) { // diagonal mask
#pragma unroll
                for (int j = 0; j < 4; ++j) {
                    int lc = 16 * j + lr;
#pragma unroll
                    for (int r = 0; r < 4; ++r) {
                        int lrow = 16 * wave + 4 * g + r;
                        if (lc > lrow) s4a[j][r] = -3e38f;
                    }
                }
            }

            // defer-max online softmax
            int cl = 1;
#pragma unroll
            for (int j = 0; j < 4; ++j)
#pragma unroll
                for (int r = 0; r < 4; ++r)
                    cl &= (s4a[j][r] <= m_r[r] + 11.0f);
            if (!__all(cl)) {
#pragma unroll
                for (int r = 0; r < 4; ++r) {
                    float mx = fmaxf(fmaxf(s4a[0][r], s4a[1][r]), fmaxf(s4a[2][r], s4a[3][r]));
#pragma unroll
                    for (int off = 1; off < 16; off <<= 1)
                        mx = fmaxf(mx, __shfl_xor(mx, off, 64));
                    float mn = fmaxf(m_r[r], mx);
                    float a = exp2f(m_r[r] - mn);
                    m_r[r] = mn;
#pragma unroll
                    for (int c = 0; c < 7; ++c) o[c][r] *= a;
                }
            }
#pragma unroll
            for (int j = 0; j < 4; ++j)
#pragma unroll
                for (int r = 0; r < 4; ++r)
                    Ps[(4 * g + r) * 72 + 16 * j + lr] = f2bf_up(exp2f(s4a[j][r] - m_r[r]));

            // PV(kt) + l (ones fragment); V from slot vcur
            const u16* Vt = VtB + vcur * 6144;
            short8 pfr[2];
#pragma unroll
            for (int kk = 0; kk < 2; ++kk)
                pfr[kk] = *(const short8*)&Ps[lr * 72 + 32 * kk + 8 * g];
            __builtin_amdgcn_s_setprio(1);
#pragma unroll
            for (int c = 0; c < 6; ++c) {
#pragma unroll
                for (int kk = 0; kk < 2; ++kk) {
                    short8 vf = *(const short8*)&Vt[(16 * c + lr) * 64 +
                                                    (((4 * kk + g) ^ (lr & 7)) << 3)];
                    o[c] = MFMA16(pfr[kk], vf, o[c]);
                }
            }
            o[6] = MFMA16(pfr[0], onesf, o[6]);
            o[6] = MFMA16(pfr[1], onesf, o[6]);
            __builtin_amdgcn_s_setprio(0);

            if (pf2) { // write tile kt+2: Ks[cur], Vt[vwr]
#pragma unroll
                for (int it = 0; it < 3; ++it) {
                    *(u32x4*)&KsB[cur * 8192 + kld[it]] = rk[it];
                    *(u32x4*)&VtB[vwr * 6144 + vld[it]] = rv[it];
                }
            }
            __syncthreads();

#pragma unroll
            for (int j = 0; j < 4; ++j) s4a[j] = s4b[j];
            vcur = (vcur == 2) ? 0 : vcur + 1;
        }

        // epilogue: write Y into qkv Q region
#pragma unroll
        for (int r = 0; r < 4; ++r) {
            int t = q0 + 16 * wave + 4 * g + r;
            float inv = 1.0f / o[6][r];
            size_t rowoff = (rowb + t) * 2304 + qcol;
#pragma unroll
            for (int c = 0; c < 6; ++c)
                qkv[rowoff + 16 * c + lr] = f2bf(o[c][r] * inv);
        }
        __syncthreads();
    }
}

// ---------------- GEMM2: 64x128 tile, 3 blocks/CU, one full residency round ----------------

__global__ __launch_bounds__(256, 3) void k_gemm_out(const u16* __restrict__ A,   // qkv, stride 2304
                                                     const u16* __restrict__ BT,  // [768][768]
                                                     const float* __restrict__ bias,
                                                     float* __restrict__ out) {
    __shared__ __align__(16) u16 lds[2 * 12288];
    const int tid = threadIdx.x;
    int id = blockIdx.x;                        // 768 blocks
    int nid = (id & 7) * 96 + (id >> 3);        // XCD-chunked remap (768 % 8 == 0)
    int by = nid / 6, bx = nid - by * 6;
    const int m0 = by * 64, n0 = bx * 128;

    const u16* Asrc = A + (size_t)m0 * 2304;
    const u16* Bsrc = BT + (size_t)n0 * 768;

    const int lane = tid & 63, wave = tid >> 6;
    const int wr = wave >> 1, wc = wave & 1;
    const int g = lane >> 4, lr = lane & 15;

    f32x4 acc[2][4];
#pragma unroll
    for (int i = 0; i < 2; ++i)
#pragma unroll
        for (int j = 0; j < 4; ++j) acc[i][j] = (f32x4){0.f, 0.f, 0.f, 0.f};

#pragma unroll
    for (int it = 0; it < 2; ++it) {
        int c = tid + it * 256;
        int r = c >> 3, s = c & 7, u = s ^ (r & 7);
        gl_lds16(&Asrc[(size_t)r * 2304 + u * 8], &lds[c * 8]);
    }
#pragma unroll
    for (int it = 0; it < 4; ++it) {
        int c = tid + it * 256;
        int r = c >> 3, s = c & 7, u = s ^ (r & 7);
        gl_lds16(&Bsrc[(size_t)r * 768 + u * 8], &lds[4096 + c * 8]);
    }
    __syncthreads();

    for (int t = 0; t < 12; ++t) {
        const int cur = t & 1;
        if (t < 11) {
            const int k0 = (t + 1) * 64;
            u16* dA = &lds[(cur ^ 1) * 12288];
            u16* dB = dA + 4096;
#pragma unroll
            for (int it = 0; it < 2; ++it) {
                int c = tid + it * 256;
                int r = c >> 3, s = c & 7, u = s ^ (r & 7);
                gl_lds16(&Asrc[(size_t)r * 2304 + k0 + u * 8], &dA[c * 8]);
            }
#pragma unroll
            for (int it = 0; it < 4; ++it) {
                int c = tid + it * 256;
                int r = c >> 3, s = c & 7, u = s ^ (r & 7);
                gl_lds16(&Bsrc[(size_t)r * 768 + k0 + u * 8], &dB[c * 8]);
            }
        }
        const u16* As = &lds[cur * 12288];
        const u16* Bs = As + 4096;
#pragma unroll
        for (int kk = 0; kk < 2; ++kk) {
            const int slot = ((4 * kk + g) ^ (lr & 7)) << 3;
            short8 af[2], bfv[4];
#pragma unroll
            for (int i = 0; i < 2; ++i)
                af[i] = *(const short8*)&As[(32 * wr + 16 * i + lr) * 64 + slot];
#pragma unroll
            for (int j = 0; j < 4; ++j)
                bfv[j] = *(const short8*)&Bs[(64 * wc + 16 * j + lr) * 64 + slot];
#pragma unroll
            for (int i = 0; i < 2; ++i)
#pragma unroll
                for (int j = 0; j < 4; ++j)
                    acc[i][j] = MFMA16(af[i], bfv[j], acc[i][j]);
        }
        if (t < 11) __syncthreads();
    }

#pragma unroll
    for (int i = 0; i < 2; ++i) {
        int row = m0 + 32 * wr + 16 * i + 4 * g;
#pragma unroll
        for (int j = 0; j < 4; ++j) {
            int col = n0 + 64 * wc + 16 * j + lr;
            float bsv = bias[col];
#pragma unroll
            for (int r = 0; r < 4; ++r)
                out[(size_t)(row + r) * 768 + col] = acc[i][j][r] + bsv;
        }
    }
}

// ---------------- launch ----------------

extern "C" void kernel_launch(void* const* d_in, const int* in_sizes, int n_in,
                              void* d_out, int out_size, void* d_ws, size_t ws_size,
                              hipStream_t stream) {
    const float* x      = (const float*)d_in[0];
    const float* w_qkv  = (const float*)d_in[1];
    const float* b_qkv  = (const float*)d_in[2];
    const float* w_proj = (const float*)d_in[3];
    const float* b_proj = (const float*)d_in[4];
    float* out = (float*)d_out;

    u16* xb    = (u16*)d_ws;            // 6291456
    u16* wqkvT = xb + 6291456;          // 1769472
    u16* wpT   = wqkvT + 1769472;       // 589824
    u16* qkv   = wpT + 589824;          // 18874368  [8192][2304]
    u16* Vtg   = qkv + 18874368;        // 6291456   [bh][96][1024]

    k_cvt<<<6720, 256, 0, stream>>>(x, w_qkv, w_proj, xb, wqkvT, wpT);
    k_gemm_qkv<<<2304, 256, 0, stream>>>(xb, wqkvT, b_qkv, qkv, Vtg);
    k_attn<<<dim3(8, 64), 256, 0, stream>>>(qkv, Vtg);
    k_gemm_out<<<768, 256, 0, stream>>>(qkv, wpT, b_proj, out);
}

// Round 20
// 105.226 us; speedup vs baseline: 1.3039x; 1.0031x over previous
//
#include <hip/hip_runtime.h>
#include <hip/hip_bf16.h>
#include <stdint.h>

typedef unsigned short u16;
typedef unsigned int u32;
typedef __attribute__((ext_vector_type(8))) short short8;
typedef __attribute__((ext_vector_type(4))) float f32x4;
typedef __attribute__((ext_vector_type(4))) unsigned int u32x4;
typedef __attribute__((ext_vector_type(4))) unsigned short u16x4;

#define MFMA16(a, b, c) __builtin_amdgcn_mfma_f32_16x16x32_bf16((a), (b), (c), 0, 0, 0)

__device__ __forceinline__ u16 f2bf(float f) {
    union { float f; uint32_t u; } v; v.f = f;
    return (u16)((v.u + 0x7FFFu + ((v.u >> 16) & 1u)) >> 16);
}
__device__ __forceinline__ u16 f2bf_up(float f) {  // round-half-up, f >= 0
    union { float f; uint32_t u; } v; v.f = f;
    return (u16)((v.u + 0x8000u) >> 16);
}

// async global -> LDS, 16 bytes per lane (dest must be linear: base + lane*16)
__device__ __forceinline__ void gl_lds16(const u16* g, u16* l) {
    __builtin_amdgcn_global_load_lds(
        (const __attribute__((address_space(1))) u32*)g,
        (__attribute__((address_space(3))) u32*)l,
        16, 0, 0);
}

// ---------------- merged convert kernel (one launch) ----------------

__global__ __launch_bounds__(256) void k_cvt(const float* __restrict__ x,
                                             const float* __restrict__ wq,
                                             const float* __restrict__ wp,
                                             u16* __restrict__ xb,
                                             u16* __restrict__ outq,
                                             u16* __restrict__ outp) {
    __shared__ u16 t[64][72];
    if (blockIdx.x < 6144) {
        int i = (blockIdx.x * 256 + threadIdx.x) * 4;
        f32x4 v = *(const f32x4*)(x + i);
        u16x4 o;
        o[0] = f2bf(v[0]); o[1] = f2bf(v[1]); o[2] = f2bf(v[2]); o[3] = f2bf(v[3]);
        *(u16x4*)(xb + i) = o;
        return;
    }
    int bid = blockIdx.x - 6144;          // 0..575
    int bx = bid % 48, kb = (bid / 48) * 64;
    const float* in; u16* out; int N, nb;
    if (bx < 36) { in = wq; out = outq; N = 2304; nb = bx * 64; }
    else         { in = wp; out = outp; N = 768;  nb = (bx - 36) * 64; }
    const int tid = threadIdx.x;
    const int r = tid >> 4, c4 = (tid & 15) << 2;
#pragma unroll
    for (int p = 0; p < 4; ++p) {
        int k = r + p * 16;
        f32x4 v = *(const f32x4*)&in[(size_t)(kb + k) * N + nb + c4];
#pragma unroll
        for (int q = 0; q < 4; ++q) t[c4 + q][k] = f2bf(v[q]);
    }
    __syncthreads();
#pragma unroll
    for (int p = 0; p < 4; ++p) {
        int nn = r + p * 16;
        u16x4 o;
#pragma unroll
        for (int q = 0; q < 4; ++q) o[q] = t[nn][c4 + q];
        *(u16x4*)&out[(size_t)(nb + nn) * 768 + kb + c4] = o;
    }
}

// ---------------- GEMM1: 64x128 tile, 3 blocks/CU, grid 2304 = exactly 3 rounds ----------------
// bx-slow per-XCD order (r19: FETCH 48->22.5MB). Each block's 128 cols lie in ONE region:
// bx 0-5 = Q, 6-11 = K, 12-17 = V. Q/K blocks use SWAPPED MFMA operands -> acc holds C^T,
// lane's 4 regs = 4 consecutive cols -> vectorized u16x4 epilogue stores (f32x4 bias loads,
// block-uniform scale). V blocks keep original order (V scatter vectorizes over t).

__global__ __launch_bounds__(256, 3) void k_gemm_qkv(const u16* __restrict__ A,
                                                     const u16* __restrict__ BT,
                                                     const float* __restrict__ bias,
                                                     u16* __restrict__ qkv,
                                                     u16* __restrict__ Vtg) {
    __shared__ __align__(16) u16 lds[2 * 12288];
    const int tid = threadIdx.x;
    int id = blockIdx.x;                        // 2304 blocks
    int local = id >> 3, xcd = id & 7;
    int bx = local >> 4;                        // 0..17, changes every 16 blocks
    int by = (xcd << 4) | (local & 15);         // XCD-private 16-row slab
    const int m0 = by * 64, n0 = bx * 128;
    const bool qkblk = (bx < 12);

    const u16* Asrc = A + (size_t)m0 * 768;
    const u16* Bsrc = BT + (size_t)n0 * 768;

    const int lane = tid & 63, wave = tid >> 6;
    const int wr = wave >> 1, wc = wave & 1;
    const int g = lane >> 4, lr = lane & 15;

    f32x4 acc[2][4];
#pragma unroll
    for (int i = 0; i < 2; ++i)
#pragma unroll
        for (int j = 0; j < 4; ++j) acc[i][j] = (f32x4){0.f, 0.f, 0.f, 0.f};

    // prologue: stage tile 0 into buf0
#pragma unroll
    for (int it = 0; it < 2; ++it) {            // A: 512 chunks
        int c = tid + it * 256;
        int r = c >> 3, s = c & 7, u = s ^ (r & 7);
        gl_lds16(&Asrc[(size_t)r * 768 + u * 8], &lds[c * 8]);
    }
#pragma unroll
    for (int it = 0; it < 4; ++it) {            // B: 1024 chunks
        int c = tid + it * 256;
        int r = c >> 3, s = c & 7, u = s ^ (r & 7);
        gl_lds16(&Bsrc[(size_t)r * 768 + u * 8], &lds[4096 + c * 8]);
    }
    __syncthreads();

    for (int t = 0; t < 12; ++t) {
        const int cur = t & 1;
        if (t < 11) {
            const int k0 = (t + 1) * 64;
            u16* dA = &lds[(cur ^ 1) * 12288];
            u16* dB = dA + 4096;
#pragma unroll
            for (int it = 0; it < 2; ++it) {
                int c = tid + it * 256;
                int r = c >> 3, s = c & 7, u = s ^ (r & 7);
                gl_lds16(&Asrc[(size_t)r * 768 + k0 + u * 8], &dA[c * 8]);
            }
#pragma unroll
            for (int it = 0; it < 4; ++it) {
                int c = tid + it * 256;
                int r = c >> 3, s = c & 7, u = s ^ (r & 7);
                gl_lds16(&Bsrc[(size_t)r * 768 + k0 + u * 8], &dB[c * 8]);
            }
        }
        const u16* As = &lds[cur * 12288];
        const u16* Bs = As + 4096;
#pragma unroll
        for (int kk = 0; kk < 2; ++kk) {
            const int slot = ((4 * kk + g) ^ (lr & 7)) << 3;
            short8 af[2], bfv[4];
#pragma unroll
            for (int i = 0; i < 2; ++i)
                af[i] = *(const short8*)&As[(32 * wr + 16 * i + lr) * 64 + slot];
#pragma unroll
            for (int j = 0; j < 4; ++j)
                bfv[j] = *(const short8*)&Bs[(64 * wc + 16 * j + lr) * 64 + slot];
            if (qkblk) { // swapped: acc = C^T (regs = consecutive cols)
#pragma unroll
                for (int i = 0; i < 2; ++i)
#pragma unroll
                    for (int j = 0; j < 4; ++j)
                        acc[i][j] = MFMA16(bfv[j], af[i], acc[i][j]);
            } else {
#pragma unroll
                for (int i = 0; i < 2; ++i)
#pragma unroll
                    for (int j = 0; j < 4; ++j)
                        acc[i][j] = MFMA16(af[i], bfv[j], acc[i][j]);
            }
        }
        if (t < 11) __syncthreads();
    }

    const float CS = 0.14724449f; // 1/sqrt(96) * log2(e)
    if (qkblk) {
        const float sc = (bx < 6) ? CS : 1.0f;
#pragma unroll
        for (int i = 0; i < 2; ++i) {
            int row = m0 + 32 * wr + 16 * i + lr;
#pragma unroll
            for (int j = 0; j < 4; ++j) {
                int col0 = n0 + 64 * wc + 16 * j + 4 * g;
                f32x4 bv = *(const f32x4*)&bias[col0];
                u16x4 y;
#pragma unroll
                for (int r = 0; r < 4; ++r)
                    y[r] = f2bf((acc[i][j][r] + bv[r]) * sc);
                *(u16x4*)&qkv[(size_t)row * 2304 + col0] = y;
            }
        }
    } else {
#pragma unroll
        for (int i = 0; i < 2; ++i) {
            int row = m0 + 32 * wr + 16 * i + 4 * g;
#pragma unroll
            for (int j = 0; j < 4; ++j) {
                int col = n0 + 64 * wc + 16 * j + lr;
                int jj = col - 1536;
                int h = jj / 96, d = jj - h * 96;
                int t2 = row & 1023, bb = row >> 10;
                int bh = bb * 8 + h;
                float bsv = bias[col];
                u16x4 vv;
#pragma unroll
                for (int r = 0; r < 4; ++r) vv[r] = f2bf(acc[i][j][r] + bsv);
                *(u16x4*)&Vtg[((size_t)bh * 96 + d) * 1024 + t2] = vv;
            }
        }
    }
}

// ---------------- flash attention (r15 proven: pipelined QK, V 3-slot, 41.7us) ----------------

__global__ __launch_bounds__(256) void k_attn(u16* __restrict__ qkv,
                                              const u16* __restrict__ Vtg) {
    __shared__ __align__(16) u16 sm[16384 + 18432 + 4608];
    u16* KsB = sm;                      // [2][64*128]
    u16* VtB = sm + 16384;              // [3][96*64]
    const int tid = threadIdx.x;
    const int wave = tid >> 6, lane = tid & 63;
    const int g = lane >> 4, lr = lane & 15;
    u16* Ps = sm + 16384 + 18432 + wave * 1152;   // [16][72]

    int id = blockIdx.y * 8 + blockIdx.x;
    int xcd = id & 7, slot = id >> 3;
    int nid = xcd * 64 + slot;
    int z = nid & 7, bh = nid >> 3;
    const int b = bh >> 3, h = bh & 7;

    const size_t rowb = (size_t)b * 1024;
    const int qcol = h * 96;
    const int kcol = 768 + h * 96;
    const size_t vbase = (size_t)bh * 96 * 1024;

    int kld[3], vld[3];
    size_t kgo[3], vgo[3];
#pragma unroll
    for (int it = 0; it < 3; ++it) {
        int c = tid + it * 256;
        int r = c / 12, s = c - r * 12;
        kgo[it] = (size_t)r * 2304 + kcol + s * 8;
        kld[it] = r * 128 + ((s ^ (r & 7)) << 3);
        int vr = c >> 3, vs = c & 7;
        vgo[it] = (size_t)vr * 1024 + vs * 8;
        vld[it] = vr * 64 + ((vs ^ (vr & 7)) << 3);
    }

    const short8 onesf = (short8){0x3F80, 0x3F80, 0x3F80, 0x3F80,
                                  0x3F80, 0x3F80, 0x3F80, 0x3F80};

    for (int seg = 0; seg < 2; ++seg) {
        const int qt = (seg == 0) ? z : 15 - z;
        const int q0 = qt * 64;

        short8 qf[3];
        {
            int qrow = q0 + 16 * wave + lr;
#pragma unroll
            for (int kk = 0; kk < 3; ++kk)
                qf[kk] = *(const short8*)&qkv[(rowb + qrow) * 2304 + qcol + 32 * kk + 8 * g];
        }

        float m_r[4];
        f32x4 o[7]; // o[6] = l (ones-MFMA accumulator)
#pragma unroll
        for (int r = 0; r < 4; ++r) m_r[r] = -3e38f;
#pragma unroll
        for (int c = 0; c < 7; ++c) o[c] = (f32x4){0.f, 0.f, 0.f, 0.f};

        u32x4 rk[3], rv[3];
        // prologue: stage tile 0 (and tile 1 if present)
#pragma unroll
        for (int it = 0; it < 3; ++it) {
            rk[it] = *(const u32x4*)&qkv[rowb * 2304 + kgo[it]];
            rv[it] = *(const u32x4*)&Vtg[vbase + vgo[it]];
        }
#pragma unroll
        for (int it = 0; it < 3; ++it) {
            *(u32x4*)&KsB[kld[it]] = rk[it];
            *(u32x4*)&VtB[vld[it]] = rv[it];
        }
        if (qt > 0) {
#pragma unroll
            for (int it = 0; it < 3; ++it) {
                rk[it] = *(const u32x4*)&qkv[(rowb + 64) * 2304 + kgo[it]];
                rv[it] = *(const u32x4*)&Vtg[vbase + 64 + vgo[it]];
            }
#pragma unroll
            for (int it = 0; it < 3; ++it) {
                *(u32x4*)&KsB[8192 + kld[it]] = rk[it];
                *(u32x4*)&VtB[6144 + vld[it]] = rv[it];
            }
        }
        __syncthreads();

        // QK(0) -> s4a
        f32x4 s4a[4], s4b[4];
        __builtin_amdgcn_s_setprio(1);
#pragma unroll
        for (int j = 0; j < 4; ++j) {
            s4a[j] = (f32x4){0.f, 0.f, 0.f, 0.f};
#pragma unroll
            for (int kk = 0; kk < 3; ++kk) {
                short8 kf = *(const short8*)&KsB[(16 * j + lr) * 128 +
                                                (((4 * kk + g) ^ (lr & 7)) << 3)];
                s4a[j] = MFMA16(qf[kk], kf, s4a[j]);
            }
        }
        __builtin_amdgcn_s_setprio(0);

        int vcur = 0; // V slot of tile kt
        for (int kt = 0; kt <= qt; ++kt) {
            const int cur = kt & 1;
            const int vwr = (vcur == 0) ? 2 : vcur - 1; // slot (kt+2)%3
            const bool pf2 = (kt + 2) <= qt;
            if (pf2) { // issue loads for tile kt+2
                const size_t nkoff = (rowb + (size_t)(kt + 2) * 64) * 2304;
                const size_t nv = vbase + (size_t)(kt + 2) * 64;
#pragma unroll
                for (int it = 0; it < 3; ++it) {
                    rk[it] = *(const u32x4*)&qkv[nkoff + kgo[it]];
                    rv[it] = *(const u32x4*)&Vtg[nv + vgo[it]];
                }
            }

            // QK(kt+1) from Ks[cur^1] (MFMA pipe) -- overlaps softmax(kt) (VALU pipe)
            if (kt < qt) {
                const u16* Ksn = KsB + (cur ^ 1) * 8192;
                __builtin_amdgcn_s_setprio(1);
#pragma unroll
                for (int j = 0; j < 4; ++j) {
                    s4b[j] = (f32x4){0.f, 0.f, 0.f, 0.f};
#pragma unroll
                    for (int kk = 0; kk < 3; ++kk) {
                        short8 kf = *(const short8*)&Ksn[(16 * j + lr) * 128 +
                                                         (((4 * kk + g) ^ (lr & 7)) << 3)];
                        s4b[j] = MFMA16(qf[kk], kf, s4b[j]);
                    }
                }
                __builtin_amdgcn_s_setprio(0);
            }

            if (kt == qt) { // diagonal mask
#pragma unroll
                for (int j = 0; j < 4; ++j) {
                    int lc = 16 * j + lr;
#pragma unroll
                    for (int r = 0; r < 4; ++r) {
                        int lrow = 16 * wave + 4 * g + r;
                        if (lc > lrow) s4a[j][r] = -3e38f;
                    }
                }
            }

            // defer-max online softmax
            int cl = 1;
#pragma unroll
            for (int j = 0; j < 4; ++j)
#pragma unroll
                for (int r = 0; r < 4; ++r)
                    cl &= (s4a[j][r] <= m_r[r] + 11.0f);
            if (!__all(cl)) {
#pragma unroll
                for (int r = 0; r < 4; ++r) {
                    float mx = fmaxf(fmaxf(s4a[0][r], s4a[1][r]), fmaxf(s4a[2][r], s4a[3][r]));
#pragma unroll
                    for (int off = 1; off < 16; off <<= 1)
                        mx = fmaxf(mx, __shfl_xor(mx, off, 64));
                    float mn = fmaxf(m_r[r], mx);
                    float a = exp2f(m_r[r] - mn);
                    m_r[r] = mn;
#pragma unroll
                    for (int c = 0; c < 7; ++c) o[c][r] *= a;
                }
            }
#pragma unroll
            for (int j = 0; j < 4; ++j)
#pragma unroll
                for (int r = 0; r < 4; ++r)
                    Ps[(4 * g + r) * 72 + 16 * j + lr] = f2bf_up(exp2f(s4a[j][r] - m_r[r]));

            // PV(kt) + l (ones fragment); V from slot vcur
            const u16* Vt = VtB + vcur * 6144;
            short8 pfr[2];
#pragma unroll
            for (int kk = 0; kk < 2; ++kk)
                pfr[kk] = *(const short8*)&Ps[lr * 72 + 32 * kk + 8 * g];
            __builtin_amdgcn_s_setprio(1);
#pragma unroll
            for (int c = 0; c < 6; ++c) {
#pragma unroll
                for (int kk = 0; kk < 2; ++kk) {
                    short8 vf = *(const short8*)&Vt[(16 * c + lr) * 64 +
                                                    (((4 * kk + g) ^ (lr & 7)) << 3)];
                    o[c] = MFMA16(pfr[kk], vf, o[c]);
                }
            }
            o[6] = MFMA16(pfr[0], onesf, o[6]);
            o[6] = MFMA16(pfr[1], onesf, o[6]);
            __builtin_amdgcn_s_setprio(0);

            if (pf2) { // write tile kt+2: Ks[cur], Vt[vwr]
#pragma unroll
                for (int it = 0; it < 3; ++it) {
                    *(u32x4*)&KsB[cur * 8192 + kld[it]] = rk[it];
                    *(u32x4*)&VtB[vwr * 6144 + vld[it]] = rv[it];
                }
            }
            __syncthreads();

#pragma unroll
            for (int j = 0; j < 4; ++j) s4a[j] = s4b[j];
            vcur = (vcur == 2) ? 0 : vcur + 1;
        }

        // epilogue: write Y into qkv Q region
#pragma unroll
        for (int r = 0; r < 4; ++r) {
            int t = q0 + 16 * wave + 4 * g + r;
            float inv = 1.0f / o[6][r];
            size_t rowoff = (rowb + t) * 2304 + qcol;
#pragma unroll
            for (int c = 0; c < 6; ++c)
                qkv[rowoff + 16 * c + lr] = f2bf(o[c][r] * inv);
        }
        __syncthreads();
    }
}

// ---------------- GEMM2: 64x128 tile, 3 blocks/CU, one full residency round ----------------

__global__ __launch_bounds__(256, 3) void k_gemm_out(const u16* __restrict__ A,   // qkv, stride 2304
                                                     const u16* __restrict__ BT,  // [768][768]
                                                     const float* __restrict__ bias,
                                                     float* __restrict__ out) {
    __shared__ __align__(16) u16 lds[2 * 12288];
    const int tid = threadIdx.x;
    int id = blockIdx.x;                        // 768 blocks
    int nid = (id & 7) * 96 + (id >> 3);        // XCD-chunked remap (768 % 8 == 0)
    int by = nid / 6, bx = nid - by * 6;
    const int m0 = by * 64, n0 = bx * 128;

    const u16* Asrc = A + (size_t)m0 * 2304;
    const u16* Bsrc = BT + (size_t)n0 * 768;

    const int lane = tid & 63, wave = tid >> 6;
    const int wr = wave >> 1, wc = wave & 1;
    const int g = lane >> 4, lr = lane & 15;

    f32x4 acc[2][4];
#pragma unroll
    for (int i = 0; i < 2; ++i)
#pragma unroll
        for (int j = 0; j < 4; ++j) acc[i][j] = (f32x4){0.f, 0.f, 0.f, 0.f};

#pragma unroll
    for (int it = 0; it < 2; ++it) {
        int c = tid + it * 256;
        int r = c >> 3, s = c & 7, u = s ^ (r & 7);
        gl_lds16(&Asrc[(size_t)r * 2304 + u * 8], &lds[c * 8]);
    }
#pragma unroll
    for (int it = 0; it < 4; ++it) {
        int c = tid + it * 256;
        int r = c >> 3, s = c & 7, u = s ^ (r & 7);
        gl_lds16(&Bsrc[(size_t)r * 768 + u * 8], &lds[4096 + c * 8]);
    }
    __syncthreads();

    for (int t = 0; t < 12; ++t) {
        const int cur = t & 1;
        if (t < 11) {
            const int k0 = (t + 1) * 64;
            u16* dA = &lds[(cur ^ 1) * 12288];
            u16* dB = dA + 4096;
#pragma unroll
            for (int it = 0; it < 2; ++it) {
                int c = tid + it * 256;
                int r = c >> 3, s = c & 7, u = s ^ (r & 7);
                gl_lds16(&Asrc[(size_t)r * 2304 + k0 + u * 8], &dA[c * 8]);
            }
#pragma unroll
            for (int it = 0; it < 4; ++it) {
                int c = tid + it * 256;
                int r = c >> 3, s = c & 7, u = s ^ (r & 7);
                gl_lds16(&Bsrc[(size_t)r * 768 + k0 + u * 8], &dB[c * 8]);
            }
        }
        const u16* As = &lds[cur * 12288];
        const u16* Bs = As + 4096;
#pragma unroll
        for (int kk = 0; kk < 2; ++kk) {
            const int slot = ((4 * kk + g) ^ (lr & 7)) << 3;
            short8 af[2], bfv[4];
#pragma unroll
            for (int i = 0; i < 2; ++i)
                af[i] = *(const short8*)&As[(32 * wr + 16 * i + lr) * 64 + slot];
#pragma unroll
            for (int j = 0; j < 4; ++j)
                bfv[j] = *(const short8*)&Bs[(64 * wc + 16 * j + lr) * 64 + slot];
#pragma unroll
            for (int i = 0; i < 2; ++i)
#pragma unroll
                for (int j = 0; j < 4; ++j)
                    acc[i][j] = MFMA16(af[i], bfv[j], acc[i][j]);
        }
        if (t < 11) __syncthreads();
    }

#pragma unroll
    for (int i = 0; i < 2; ++i) {
        int row = m0 + 32 * wr + 16 * i + 4 * g;
#pragma unroll
        for (int j = 0; j < 4; ++j) {
            int col = n0 + 64 * wc + 16 * j + lr;
            float bsv = bias[col];
#pragma unroll
            for (int r = 0; r < 4; ++r)
                out[(size_t)(row + r) * 768 + col] = acc[i][j][r] + bsv;
        }
    }
}

// ---------------- launch ----------------

extern "C" void kernel_launch(void* const* d_in, const int* in_sizes, int n_in,
                              void* d_out, int out_size, void* d_ws, size_t ws_size,
                              hipStream_t stream) {
    const float* x      = (const float*)d_in[0];
    const float* w_qkv  = (const float*)d_in[1];
    const float* b_qkv  = (const float*)d_in[2];
    const float* w_proj = (const float*)d_in[3];
    const float* b_proj = (const float*)d_in[4];
    float* out = (float*)d_out;

    u16* xb    = (u16*)d_ws;            // 6291456
    u16* wqkvT = xb + 6291456;          // 1769472
    u16* wpT   = wqkvT + 1769472;       // 589824
    u16* qkv   = wpT + 589824;          // 18874368  [8192][2304]
    u16* Vtg   = qkv + 18874368;        // 6291456   [bh][96][1024]

    k_cvt<<<6720, 256, 0, stream>>>(x, w_qkv, w_proj, xb, wqkvT, wpT);
    k_gemm_qkv<<<2304, 256, 0, stream>>>(xb, wqkvT, b_qkv, qkv, Vtg);
    k_attn<<<dim3(8, 64), 256, 0, stream>>>(qkv, Vtg);
    k_gemm_out<<<768, 256, 0, stream>>>(qkv, wpT, b_proj, out);
}

// Round 21
// 103.649 us; speedup vs baseline: 1.3237x; 1.0152x over previous
//
#include <hip/hip_runtime.h>
#include <hip/hip_bf16.h>
#include <stdint.h>

typedef unsigned short u16;
typedef unsigned int u32;
typedef __attribute__((ext_vector_type(8))) short short8;
typedef __attribute__((ext_vector_type(4))) float f32x4;
typedef __attribute__((ext_vector_type(4))) unsigned int u32x4;
typedef __attribute__((ext_vector_type(4))) unsigned short u16x4;

#define MFMA16(a, b, c) __builtin_amdgcn_mfma_f32_16x16x32_bf16((a), (b), (c), 0, 0, 0)

__device__ __forceinline__ u16 f2bf(float f) {
    union { float f; uint32_t u; } v; v.f = f;
    return (u16)((v.u + 0x7FFFu + ((v.u >> 16) & 1u)) >> 16);
}
__device__ __forceinline__ u16 f2bf_up(float f) {  // round-half-up, f >= 0
    union { float f; uint32_t u; } v; v.f = f;
    return (u16)((v.u + 0x8000u) >> 16);
}

// async global -> LDS, 16 bytes per lane (dest must be linear: base + lane*16)
__device__ __forceinline__ void gl_lds16(const u16* g, u16* l) {
    __builtin_amdgcn_global_load_lds(
        (const __attribute__((address_space(1))) u32*)g,
        (__attribute__((address_space(3))) u32*)l,
        16, 0, 0);
}

// ---------------- merged convert kernel (one launch) ----------------
// blocks 0..3071: x f32 -> bf16, 8 elems (32B) per thread. blocks 3072..3647: weight transpose.

__global__ __launch_bounds__(256) void k_cvt(const float* __restrict__ x,
                                             const float* __restrict__ wq,
                                             const float* __restrict__ wp,
                                             u16* __restrict__ xb,
                                             u16* __restrict__ outq,
                                             u16* __restrict__ outp) {
    __shared__ u16 t[64][72];
    if (blockIdx.x < 3072) {
        int i = (blockIdx.x * 256 + threadIdx.x) * 8;
        f32x4 v0 = *(const f32x4*)(x + i);
        f32x4 v1 = *(const f32x4*)(x + i + 4);
        u16x4 o0, o1;
#pragma unroll
        for (int q = 0; q < 4; ++q) { o0[q] = f2bf(v0[q]); o1[q] = f2bf(v1[q]); }
        *(u16x4*)(xb + i) = o0;
        *(u16x4*)(xb + i + 4) = o1;
        return;
    }
    int bid = blockIdx.x - 3072;          // 0..575
    int bx = bid % 48, kb = (bid / 48) * 64;
    const float* in; u16* out; int N, nb;
    if (bx < 36) { in = wq; out = outq; N = 2304; nb = bx * 64; }
    else         { in = wp; out = outp; N = 768;  nb = (bx - 36) * 64; }
    const int tid = threadIdx.x;
    const int r = tid >> 4, c4 = (tid & 15) << 2;
#pragma unroll
    for (int p = 0; p < 4; ++p) {
        int k = r + p * 16;
        f32x4 v = *(const f32x4*)&in[(size_t)(kb + k) * N + nb + c4];
#pragma unroll
        for (int q = 0; q < 4; ++q) t[c4 + q][k] = f2bf(v[q]);
    }
    __syncthreads();
#pragma unroll
    for (int p = 0; p < 4; ++p) {
        int nn = r + p * 16;
        u16x4 o;
#pragma unroll
        for (int q = 0; q < 4; ++q) o[q] = t[nn][c4 + q];
        *(u16x4*)&out[(size_t)(nb + nn) * 768 + kb + c4] = o;
    }
}

// ---------------- GEMM1: 64x128 tile, 3 blocks/CU, grid 2304 = exactly 3 rounds ----------------
// bx-slow per-XCD order (r19: FETCH 48->22.5MB, XCD-private A slab).
// Q (cols<768, pre-scaled by 1/sqrt(96)*log2e) and K -> qkv rows; V -> Vtg[bh][d][t].

__global__ __launch_bounds__(256, 3) void k_gemm_qkv(const u16* __restrict__ A,
                                                     const u16* __restrict__ BT,
                                                     const float* __restrict__ bias,
                                                     u16* __restrict__ qkv,
                                                     u16* __restrict__ Vtg) {
    __shared__ __align__(16) u16 lds[2 * 12288];
    const int tid = threadIdx.x;
    int id = blockIdx.x;                        // 2304 blocks
    int local = id >> 3, xcd = id & 7;
    int bx = local >> 4;                        // 0..17, changes every 16 blocks
    int by = (xcd << 4) | (local & 15);         // XCD-private 16-row slab
    const int m0 = by * 64, n0 = bx * 128;

    const u16* Asrc = A + (size_t)m0 * 768;
    const u16* Bsrc = BT + (size_t)n0 * 768;

    const int lane = tid & 63, wave = tid >> 6;
    const int wr = wave >> 1, wc = wave & 1;
    const int g = lane >> 4, lr = lane & 15;

    f32x4 acc[2][4];
#pragma unroll
    for (int i = 0; i < 2; ++i)
#pragma unroll
        for (int j = 0; j < 4; ++j) acc[i][j] = (f32x4){0.f, 0.f, 0.f, 0.f};

    // prologue: stage tile 0 into buf0
#pragma unroll
    for (int it = 0; it < 2; ++it) {            // A: 512 chunks
        int c = tid + it * 256;
        int r = c >> 3, s = c & 7, u = s ^ (r & 7);
        gl_lds16(&Asrc[(size_t)r * 768 + u * 8], &lds[c * 8]);
    }
#pragma unroll
    for (int it = 0; it < 4; ++it) {            // B: 1024 chunks
        int c = tid + it * 256;
        int r = c >> 3, s = c & 7, u = s ^ (r & 7);
        gl_lds16(&Bsrc[(size_t)r * 768 + u * 8], &lds[4096 + c * 8]);
    }
    __syncthreads();

    for (int t = 0; t < 12; ++t) {
        const int cur = t & 1;
        if (t < 11) {
            const int k0 = (t + 1) * 64;
            u16* dA = &lds[(cur ^ 1) * 12288];
            u16* dB = dA + 4096;
#pragma unroll
            for (int it = 0; it < 2; ++it) {
                int c = tid + it * 256;
                int r = c >> 3, s = c & 7, u = s ^ (r & 7);
                gl_lds16(&Asrc[(size_t)r * 768 + k0 + u * 8], &dA[c * 8]);
            }
#pragma unroll
            for (int it = 0; it < 4; ++it) {
                int c = tid + it * 256;
                int r = c >> 3, s = c & 7, u = s ^ (r & 7);
                gl_lds16(&Bsrc[(size_t)r * 768 + k0 + u * 8], &dB[c * 8]);
            }
        }
        const u16* As = &lds[cur * 12288];
        const u16* Bs = As + 4096;
#pragma unroll
        for (int kk = 0; kk < 2; ++kk) {
            const int slot = ((4 * kk + g) ^ (lr & 7)) << 3;
            short8 af[2], bfv[4];
#pragma unroll
            for (int i = 0; i < 2; ++i)
                af[i] = *(const short8*)&As[(32 * wr + 16 * i + lr) * 64 + slot];
#pragma unroll
            for (int j = 0; j < 4; ++j)
                bfv[j] = *(const short8*)&Bs[(64 * wc + 16 * j + lr) * 64 + slot];
#pragma unroll
            for (int i = 0; i < 2; ++i)
#pragma unroll
                for (int j = 0; j < 4; ++j)
                    acc[i][j] = MFMA16(af[i], bfv[j], acc[i][j]);
        }
        if (t < 11) __syncthreads();
    }

    const float CS = 0.14724449f; // 1/sqrt(96) * log2(e)
#pragma unroll
    for (int i = 0; i < 2; ++i) {
        int row = m0 + 32 * wr + 16 * i + 4 * g;
#pragma unroll
        for (int j = 0; j < 4; ++j) {
            int col = n0 + 64 * wc + 16 * j + lr;
            float bsv = bias[col];
            if (col < 1536) {
                float sc = (col < 768) ? CS : 1.0f;
#pragma unroll
                for (int r = 0; r < 4; ++r)
                    qkv[(size_t)(row + r) * 2304 + col] = f2bf((acc[i][j][r] + bsv) * sc);
            } else {
                int jj = col - 1536;
                int h = jj / 96, d = jj - h * 96;
                int t2 = row & 1023, bb = row >> 10;
                int bh = bb * 8 + h;
                u16x4 vv;
#pragma unroll
                for (int r = 0; r < 4; ++r) vv[r] = f2bf(acc[i][j][r] + bsv);
                *(u16x4*)&Vtg[((size_t)bh * 96 + d) * 1024 + t2] = vv;
            }
        }
    }
}

// ---------------- flash attention (r15 proven: pipelined QK, V 3-slot, 41.7us) ----------------

__global__ __launch_bounds__(256) void k_attn(u16* __restrict__ qkv,
                                              const u16* __restrict__ Vtg) {
    __shared__ __align__(16) u16 sm[16384 + 18432 + 4608];
    u16* KsB = sm;                      // [2][64*128]
    u16* VtB = sm + 16384;              // [3][96*64]
    const int tid = threadIdx.x;
    const int wave = tid >> 6, lane = tid & 63;
    const int g = lane >> 4, lr = lane & 15;
    u16* Ps = sm + 16384 + 18432 + wave * 1152;   // [16][72]

    int id = blockIdx.y * 8 + blockIdx.x;
    int xcd = id & 7, slot = id >> 3;
    int nid = xcd * 64 + slot;
    int z = nid & 7, bh = nid >> 3;
    const int b = bh >> 3, h = bh & 7;

    const size_t rowb = (size_t)b * 1024;
    const int qcol = h * 96;
    const int kcol = 768 + h * 96;
    const size_t vbase = (size_t)bh * 96 * 1024;

    int kld[3], vld[3];
    size_t kgo[3], vgo[3];
#pragma unroll
    for (int it = 0; it < 3; ++it) {
        int c = tid + it * 256;
        int r = c / 12, s = c - r * 12;
        kgo[it] = (size_t)r * 2304 + kcol + s * 8;
        kld[it] = r * 128 + ((s ^ (r & 7)) << 3);
        int vr = c >> 3, vs = c & 7;
        vgo[it] = (size_t)vr * 1024 + vs * 8;
        vld[it] = vr * 64 + ((vs ^ (vr & 7)) << 3);
    }

    const short8 onesf = (short8){0x3F80, 0x3F80, 0x3F80, 0x3F80,
                                  0x3F80, 0x3F80, 0x3F80, 0x3F80};

    for (int seg = 0; seg < 2; ++seg) {
        const int qt = (seg == 0) ? z : 15 - z;
        const int q0 = qt * 64;

        short8 qf[3];
        {
            int qrow = q0 + 16 * wave + lr;
#pragma unroll
            for (int kk = 0; kk < 3; ++kk)
                qf[kk] = *(const short8*)&qkv[(rowb + qrow) * 2304 + qcol + 32 * kk + 8 * g];
        }

        float m_r[4];
        f32x4 o[7]; // o[6] = l (ones-MFMA accumulator)
#pragma unroll
        for (int r = 0; r < 4; ++r) m_r[r] = -3e38f;
#pragma unroll
        for (int c = 0; c < 7; ++c) o[c] = (f32x4){0.f, 0.f, 0.f, 0.f};

        u32x4 rk[3], rv[3];
        // prologue: stage tile 0 (and tile 1 if present)
#pragma unroll
        for (int it = 0; it < 3; ++it) {
            rk[it] = *(const u32x4*)&qkv[rowb * 2304 + kgo[it]];
            rv[it] = *(const u32x4*)&Vtg[vbase + vgo[it]];
        }
#pragma unroll
        for (int it = 0; it < 3; ++it) {
            *(u32x4*)&KsB[kld[it]] = rk[it];
            *(u32x4*)&VtB[vld[it]] = rv[it];
        }
        if (qt > 0) {
#pragma unroll
            for (int it = 0; it < 3; ++it) {
                rk[it] = *(const u32x4*)&qkv[(rowb + 64) * 2304 + kgo[it]];
                rv[it] = *(const u32x4*)&Vtg[vbase + 64 + vgo[it]];
            }
#pragma unroll
            for (int it = 0; it < 3; ++it) {
                *(u32x4*)&KsB[8192 + kld[it]] = rk[it];
                *(u32x4*)&VtB[6144 + vld[it]] = rv[it];
            }
        }
        __syncthreads();

        // QK(0) -> s4a
        f32x4 s4a[4], s4b[4];
        __builtin_amdgcn_s_setprio(1);
#pragma unroll
        for (int j = 0; j < 4; ++j) {
            s4a[j] = (f32x4){0.f, 0.f, 0.f, 0.f};
#pragma unroll
            for (int kk = 0; kk < 3; ++kk) {
                short8 kf = *(const short8*)&KsB[(16 * j + lr) * 128 +
                                                (((4 * kk + g) ^ (lr & 7)) << 3)];
                s4a[j] = MFMA16(qf[kk], kf, s4a[j]);
            }
        }
        __builtin_amdgcn_s_setprio(0);

        int vcur = 0; // V slot of tile kt
        for (int kt = 0; kt <= qt; ++kt) {
            const int cur = kt & 1;
            const int vwr = (vcur == 0) ? 2 : vcur - 1; // slot (kt+2)%3
            const bool pf2 = (kt + 2) <= qt;
            if (pf2) { // issue loads for tile kt+2
                const size_t nkoff = (rowb + (size_t)(kt + 2) * 64) * 2304;
                const size_t nv = vbase + (size_t)(kt + 2) * 64;
#pragma unroll
                for (int it = 0; it < 3; ++it) {
                    rk[it] = *(const u32x4*)&qkv[nkoff + kgo[it]];
                    rv[it] = *(const u32x4*)&Vtg[nv + vgo[it]];
                }
            }

            // QK(kt+1) from Ks[cur^1] (MFMA pipe) -- overlaps softmax(kt) (VALU pipe)
            if (kt < qt) {
                const u16* Ksn = KsB + (cur ^ 1) * 8192;
                __builtin_amdgcn_s_setprio(1);
#pragma unroll
                for (int j = 0; j < 4; ++j) {
                    s4b[j] = (f32x4){0.f, 0.f, 0.f, 0.f};
#pragma unroll
                    for (int kk = 0; kk < 3; ++kk) {
                        short8 kf = *(const short8*)&Ksn[(16 * j + lr) * 128 +
                                                         (((4 * kk + g) ^ (lr & 7)) << 3)];
                        s4b[j] = MFMA16(qf[kk], kf, s4b[j]);
                    }
                }
                __builtin_amdgcn_s_setprio(0);
            }

            if (kt == qt) { // diagonal mask
#pragma unroll
                for (int j = 0; j < 4; ++j) {
                    int lc = 16 * j + lr;
#pragma unroll
                    for (int r = 0; r < 4; ++r) {
                        int lrow = 16 * wave + 4 * g + r;
                        if (lc > lrow) s4a[j][r] = -3e38f;
                    }
                }
            }

            // defer-max online softmax
            int cl = 1;
#pragma unroll
            for (int j = 0; j < 4; ++j)
#pragma unroll
                for (int r = 0; r < 4; ++r)
                    cl &= (s4a[j][r] <= m_r[r] + 11.0f);
            if (!__all(cl)) {
#pragma unroll
                for (int r = 0; r < 4; ++r) {
                    float mx = fmaxf(fmaxf(s4a[0][r], s4a[1][r]), fmaxf(s4a[2][r], s4a[3][r]));
#pragma unroll
                    for (int off = 1; off < 16; off <<= 1)
                        mx = fmaxf(mx, __shfl_xor(mx, off, 64));
                    float mn = fmaxf(m_r[r], mx);
                    float a = exp2f(m_r[r] - mn);
                    m_r[r] = mn;
#pragma unroll
                    for (int c = 0; c < 7; ++c) o[c][r] *= a;
                }
            }
#pragma unroll
            for (int j = 0; j < 4; ++j)
#pragma unroll
                for (int r = 0; r < 4; ++r)
                    Ps[(4 * g + r) * 72 + 16 * j + lr] = f2bf_up(exp2f(s4a[j][r] - m_r[r]));

            // PV(kt) + l (ones fragment); V from slot vcur
            const u16* Vt = VtB + vcur * 6144;
            short8 pfr[2];
#pragma unroll
            for (int kk = 0; kk < 2; ++kk)
                pfr[kk] = *(const short8*)&Ps[lr * 72 + 32 * kk + 8 * g];
            __builtin_amdgcn_s_setprio(1);
#pragma unroll
            for (int c = 0; c < 6; ++c) {
#pragma unroll
                for (int kk = 0; kk < 2; ++kk) {
                    short8 vf = *(const short8*)&Vt[(16 * c + lr) * 64 +
                                                    (((4 * kk + g) ^ (lr & 7)) << 3)];
                    o[c] = MFMA16(pfr[kk], vf, o[c]);
                }
            }
            o[6] = MFMA16(pfr[0], onesf, o[6]);
            o[6] = MFMA16(pfr[1], onesf, o[6]);
            __builtin_amdgcn_s_setprio(0);

            if (pf2) { // write tile kt+2: Ks[cur], Vt[vwr]
#pragma unroll
                for (int it = 0; it < 3; ++it) {
                    *(u32x4*)&KsB[cur * 8192 + kld[it]] = rk[it];
                    *(u32x4*)&VtB[vwr * 6144 + vld[it]] = rv[it];
                }
            }
            __syncthreads();

#pragma unroll
            for (int j = 0; j < 4; ++j) s4a[j] = s4b[j];
            vcur = (vcur == 2) ? 0 : vcur + 1;
        }

        // epilogue: write Y into qkv Q region
#pragma unroll
        for (int r = 0; r < 4; ++r) {
            int t = q0 + 16 * wave + 4 * g + r;
            float inv = 1.0f / o[6][r];
            size_t rowoff = (rowb + t) * 2304 + qcol;
#pragma unroll
            for (int c = 0; c < 6; ++c)
                qkv[rowoff + 16 * c + lr] = f2bf(o[c][r] * inv);
        }
        __syncthreads();
    }
}

// ---------------- GEMM2: 64x128 tile, 3 blocks/CU, one full residency round ----------------

__global__ __launch_bounds__(256, 3) void k_gemm_out(const u16* __restrict__ A,   // qkv, stride 2304
                                                     const u16* __restrict__ BT,  // [768][768]
                                                     const float* __restrict__ bias,
                                                     float* __restrict__ out) {
    __shared__ __align__(16) u16 lds[2 * 12288];
    const int tid = threadIdx.x;
    int id = blockIdx.x;                        // 768 blocks
    int nid = (id & 7) * 96 + (id >> 3);        // XCD-chunked remap (768 % 8 == 0)
    int by = nid / 6, bx = nid - by * 6;
    const int m0 = by * 64, n0 = bx * 128;

    const u16* Asrc = A + (size_t)m0 * 2304;
    const u16* Bsrc = BT + (size_t)n0 * 768;

    const int lane = tid & 63, wave = tid >> 6;
    const int wr = wave >> 1, wc = wave & 1;
    const int g = lane >> 4, lr = lane & 15;

    f32x4 acc[2][4];
#pragma unroll
    for (int i = 0; i < 2; ++i)
#pragma unroll
        for (int j = 0; j < 4; ++j) acc[i][j] = (f32x4){0.f, 0.f, 0.f, 0.f};

#pragma unroll
    for (int it = 0; it < 2; ++it) {
        int c = tid + it * 256;
        int r = c >> 3, s = c & 7, u = s ^ (r & 7);
        gl_lds16(&Asrc[(size_t)r * 2304 + u * 8], &lds[c * 8]);
    }
#pragma unroll
    for (int it = 0; it < 4; ++it) {
        int c = tid + it * 256;
        int r = c >> 3, s = c & 7, u = s ^ (r & 7);
        gl_lds16(&Bsrc[(size_t)r * 768 + u * 8], &lds[4096 + c * 8]);
    }
    __syncthreads();

    for (int t = 0; t < 12; ++t) {
        const int cur = t & 1;
        if (t < 11) {
            const int k0 = (t + 1) * 64;
            u16* dA = &lds[(cur ^ 1) * 12288];
            u16* dB = dA + 4096;
#pragma unroll
            for (int it = 0; it < 2; ++it) {
                int c = tid + it * 256;
                int r = c >> 3, s = c & 7, u = s ^ (r & 7);
                gl_lds16(&Asrc[(size_t)r * 2304 + k0 + u * 8], &dA[c * 8]);
            }
#pragma unroll
            for (int it = 0; it < 4; ++it) {
                int c = tid + it * 256;
                int r = c >> 3, s = c & 7, u = s ^ (r & 7);
                gl_lds16(&Bsrc[(size_t)r * 768 + k0 + u * 8], &dB[c * 8]);
            }
        }
        const u16* As = &lds[cur * 12288];
        const u16* Bs = As + 4096;
#pragma unroll
        for (int kk = 0; kk < 2; ++kk) {
            const int slot = ((4 * kk + g) ^ (lr & 7)) << 3;
            short8 af[2], bfv[4];
#pragma unroll
            for (int i = 0; i < 2; ++i)
                af[i] = *(const short8*)&As[(32 * wr + 16 * i + lr) * 64 + slot];
#pragma unroll
            for (int j = 0; j < 4; ++j)
                bfv[j] = *(const short8*)&Bs[(64 * wc + 16 * j + lr) * 64 + slot];
#pragma unroll
            for (int i = 0; i < 2; ++i)
#pragma unroll
                for (int j = 0; j < 4; ++j)
                    acc[i][j] = MFMA16(af[i], bfv[j], acc[i][j]);
        }
        if (t < 11) __syncthreads();
    }

#pragma unroll
    for (int i = 0; i < 2; ++i) {
        int row = m0 + 32 * wr + 16 * i + 4 * g;
#pragma unroll
        for (int j = 0; j < 4; ++j) {
            int col = n0 + 64 * wc + 16 * j + lr;
            float bsv = bias[col];
#pragma unroll
            for (int r = 0; r < 4; ++r)
                out[(size_t)(row + r) * 768 + col] = acc[i][j][r] + bsv;
        }
    }
}

// ---------------- launch ----------------

extern "C" void kernel_launch(void* const* d_in, const int* in_sizes, int n_in,
                              void* d_out, int out_size, void* d_ws, size_t ws_size,
                              hipStream_t stream) {
    const float* x      = (const float*)d_in[0];
    const float* w_qkv  = (const float*)d_in[1];
    const float* b_qkv  = (const float*)d_in[2];
    const float* w_proj = (const float*)d_in[3];
    const float* b_proj = (const float*)d_in[4];
    float* out = (float*)d_out;

    u16* xb    = (u16*)d_ws;            // 6291456
    u16* wqkvT = xb + 6291456;          // 1769472
    u16* wpT   = wqkvT + 1769472;       // 589824
    u16* qkv   = wpT + 589824;          // 18874368  [8192][2304]
    u16* Vtg   = qkv + 18874368;        // 6291456   [bh][96][1024]

    k_cvt<<<3648, 256, 0, stream>>>(x, w_qkv, w_proj, xb, wqkvT, wpT);
    k_gemm_qkv<<<2304, 256, 0, stream>>>(xb, wqkvT, b_qkv, qkv, Vtg);
    k_attn<<<dim3(8, 64), 256, 0, stream>>>(qkv, Vtg);
    k_gemm_out<<<768, 256, 0, stream>>>(qkv, wpT, b_proj, out);
}